// Round 2
// baseline (551.887 us; speedup 1.0000x reference)
//
#include <hip/hip_runtime.h>
#include <hip/hip_bf16.h>
#include <math.h>

// DscaGRUCell — fp32 correctness baseline, rev 2.
// Fix vs rev 1: reference GRU is reset-BEFORE on the candidate path:
//   hh = tanh(x_h + (r * h_prev) @ rk[:, 2U:])   (Python * and @ are
//   same-precedence left-assoc), and mi = h_prev @ rk[:, :2U] only.

#define TAU_F 0.5f

// ---------------- generic fp32 GEMM: 64x64 tile, BK=8, 256 thr, 4x4 micro ----
// EPI: 0 = AB ; 1 = AB+bias ; 2 = tanh(AB+bias) ; 3 = base + tanh(AB+bias)
template <int EPI>
__global__ __launch_bounds__(256) void gemm64(
    const float* __restrict__ A, int lda,
    const float* __restrict__ B, int ldb,
    float* __restrict__ C, int ldc, int K,
    const float* __restrict__ bias,
    const float* __restrict__ base, int ldbase)
{
    __shared__ float As[8][64];
    __shared__ float Bs[8][64];
    const int tid = threadIdx.x;
    const int tx = tid & 15, ty = tid >> 4;
    const int brow = blockIdx.y * 64;
    const int bcol = blockIdx.x * 64;

    const int ar  = tid >> 2;         // 0..63
    const int ak  = (tid & 3) * 2;    // 0,2,4,6
    const int bkk = tid >> 5;         // 0..7
    const int bn  = (tid & 31) * 2;   // 0..62

    const float* Ap = A + (size_t)(brow + ar) * lda + ak;
    const float* Bp = B + (size_t)bkk * ldb + bcol + bn;

    float acc[4][4];
#pragma unroll
    for (int i = 0; i < 4; ++i)
#pragma unroll
        for (int j = 0; j < 4; ++j) acc[i][j] = 0.f;

    for (int k0 = 0; k0 < K; k0 += 8) {
        float2 av = *(const float2*)Ap;
        float2 bv = *(const float2*)Bp;
        __syncthreads();
        As[ak][ar]     = av.x;
        As[ak + 1][ar] = av.y;
        *(float2*)&Bs[bkk][bn] = bv;
        __syncthreads();
        Ap += 8;
        Bp += (size_t)8 * ldb;
#pragma unroll
        for (int kk = 0; kk < 8; ++kk) {
            float4 a = *(const float4*)&As[kk][ty * 4];
            float4 b = *(const float4*)&Bs[kk][tx * 4];
            float aa[4] = {a.x, a.y, a.z, a.w};
            float bb[4] = {b.x, b.y, b.z, b.w};
#pragma unroll
            for (int i = 0; i < 4; ++i)
#pragma unroll
                for (int j = 0; j < 4; ++j)
                    acc[i][j] = fmaf(aa[i], bb[j], acc[i][j]);
        }
    }

    const int row = brow + ty * 4;
    const int col = bcol + tx * 4;
#pragma unroll
    for (int i = 0; i < 4; ++i) {
        float t[4];
#pragma unroll
        for (int j = 0; j < 4; ++j) {
            float s = acc[i][j];
            if (EPI >= 1) s += bias[col + j];
            if (EPI >= 2) s = tanhf(s);
            if (EPI == 3) s += base[(size_t)(row + i) * ldbase + col + j];
            t[j] = s;
        }
        float4 v = {t[0], t[1], t[2], t[3]};
        *(float4*)&C[(size_t)(row + i) * ldc + col] = v;
    }
}

// paired GEMM (EPI=0): blocks bx<gxHalf use set 0, else set 1. For emb1/emb2.
__global__ __launch_bounds__(256) void gemm64_pair(
    const float* __restrict__ A0, const float* __restrict__ A1, int lda,
    const float* __restrict__ B0, const float* __restrict__ B1, int ldb,
    float* __restrict__ C0, float* __restrict__ C1, int ldc,
    int K, int gxHalf)
{
    __shared__ float As[8][64];
    __shared__ float Bs[8][64];
    const int tid = threadIdx.x;
    const int tx = tid & 15, ty = tid >> 4;
    const bool second = (int)blockIdx.x >= gxHalf;
    const float* A = second ? A1 : A0;
    const float* B = second ? B1 : B0;
    float* C = second ? C1 : C0;
    const int bxl = second ? (blockIdx.x - gxHalf) : blockIdx.x;
    const int brow = blockIdx.y * 64;
    const int bcol = bxl * 64;

    const int ar  = tid >> 2;
    const int ak  = (tid & 3) * 2;
    const int bkk = tid >> 5;
    const int bn  = (tid & 31) * 2;

    const float* Ap = A + (size_t)(brow + ar) * lda + ak;
    const float* Bp = B + (size_t)bkk * ldb + bcol + bn;

    float acc[4][4];
#pragma unroll
    for (int i = 0; i < 4; ++i)
#pragma unroll
        for (int j = 0; j < 4; ++j) acc[i][j] = 0.f;

    for (int k0 = 0; k0 < K; k0 += 8) {
        float2 av = *(const float2*)Ap;
        float2 bv = *(const float2*)Bp;
        __syncthreads();
        As[ak][ar]     = av.x;
        As[ak + 1][ar] = av.y;
        *(float2*)&Bs[bkk][bn] = bv;
        __syncthreads();
        Ap += 8;
        Bp += (size_t)8 * ldb;
#pragma unroll
        for (int kk = 0; kk < 8; ++kk) {
            float4 a = *(const float4*)&As[kk][ty * 4];
            float4 b = *(const float4*)&Bs[kk][tx * 4];
            float aa[4] = {a.x, a.y, a.z, a.w};
            float bb[4] = {b.x, b.y, b.z, b.w};
#pragma unroll
            for (int i = 0; i < 4; ++i)
#pragma unroll
                for (int j = 0; j < 4; ++j)
                    acc[i][j] = fmaf(aa[i], bb[j], acc[i][j]);
        }
    }

    const int row = brow + ty * 4;
    const int col = bcol + tx * 4;
#pragma unroll
    for (int i = 0; i < 4; ++i) {
        float4 v = {acc[i][0], acc[i][1], acc[i][2], acc[i][3]};
        *(float4*)&C[(size_t)(row + i) * ldc + col] = v;
    }
}

// ---------------- pack the 512x1024 combined attention weight --------------
__global__ __launch_bounds__(256) void pack_wcat(
    const float* __restrict__ w12, const float* __restrict__ u12,
    const float* __restrict__ v12, const float* __restrict__ w21,
    const float* __restrict__ u21, const float* __restrict__ v21,
    float* __restrict__ Wcat)
{
    int i = blockIdx.x * 256 + threadIdx.x;
    if (i >= 512 * 1024) return;
    int k = i >> 10, j = i & 1023;
    int jm = j & 255;
    float val;
    if (j < 256)      val = (k < 256) ? w12[k * 256 + jm] : u12[(k - 256) * 256 + jm];
    else if (j < 512) val = (k < 256) ? u21[k * 256 + jm] : w21[(k - 256) * 256 + jm];
    else if (j < 768) val = (k < 256) ? 0.f               : v12[(k - 256) * 256 + jm];
    else              val = (k < 256) ? v21[k * 256 + jm] : 0.f;
    Wcat[i] = val;
}

// ---------------- attention softmax fuse ------------------------------------
__device__ inline float block_reduce_max(float v, volatile float* s4) {
#pragma unroll
    for (int o = 32; o >= 1; o >>= 1) v = fmaxf(v, __shfl_xor(v, o, 64));
    __syncthreads();
    if ((threadIdx.x & 63) == 0) s4[threadIdx.x >> 6] = v;
    __syncthreads();
    return fmaxf(fmaxf(s4[0], s4[1]), fmaxf(s4[2], s4[3]));
}
__device__ inline float block_reduce_sum(float v, volatile float* s4) {
#pragma unroll
    for (int o = 32; o >= 1; o >>= 1) v += __shfl_xor(v, o, 64);
    __syncthreads();
    if ((threadIdx.x & 63) == 0) s4[threadIdx.x >> 6] = v;
    __syncthreads();
    return s4[0] + s4[1] + s4[2] + s4[3];
}

__global__ __launch_bounds__(256) void att_fuse(
    const float* __restrict__ T, const float* __restrict__ E,
    const float* __restrict__ crohis, float* __restrict__ x,
    float* __restrict__ cro_new)
{
    __shared__ float s4[4];
    const int row = blockIdx.x;
    const int j = threadIdx.x;
    const float* t = T + (size_t)row * 1024;

    float s12 = tanhf(t[j])       * t[512 + j];
    float s21 = tanhf(t[256 + j]) * t[768 + j];

    float m12 = block_reduce_max(s12, s4);
    float e12 = expf(s12 - m12);
    float sum12 = block_reduce_sum(e12, s4);
    float m21 = block_reduce_max(s21, s4);
    float e21 = expf(s21 - m21);
    float sum21 = block_reduce_sum(e21, s4);

    float att12 = e12 / sum12;
    float att21 = e21 / sum21;

    size_t b0 = (size_t)row * 512 + j;
    size_t b1 = b0 + 256;
    float x1 = E[b0] * att12;
    float x2 = E[b1] * att21;
    x[b0] = x1;
    x[b1] = x2;
    cro_new[b0] = TAU_F * crohis[b0] + (1.f - TAU_F) * x1;
    cro_new[b1] = TAU_F * crohis[b1] + (1.f - TAU_F) * x2;
}

// ---------------- GRU gates: rh = sigmoid(x_r + mi_r) * h_prev --------------
__global__ __launch_bounds__(256) void gru_gates(
    const float* __restrict__ mx, const float* __restrict__ mi2,
    const float* __restrict__ hprev, float* __restrict__ rh)
{
    int i = blockIdx.x * 256 + threadIdx.x;   // 0 .. 4096*512
    int row = i >> 9, col = i & 511;
    float xr  = mx[(size_t)row * 1536 + 512 + col];
    float mir = mi2[(size_t)row * 1024 + 512 + col];
    float r = 1.f / (1.f + expf(-(xr + mir)));
    rh[i] = r * hprev[i];
}

// ---------------- GRU finalize ----------------------------------------------
__global__ __launch_bounds__(256) void gru_final(
    const float* __restrict__ mx, const float* __restrict__ mi2,
    const float* __restrict__ mh, const float* __restrict__ hprev,
    float* __restrict__ h)
{
    int i = blockIdx.x * 256 + threadIdx.x;   // 0 .. 4096*512
    int row = i >> 9, col = i & 511;
    const float* mxr = mx + (size_t)row * 1536;
    float xz = mxr[col], xh = mxr[1024 + col];
    float miz = mi2[(size_t)row * 1024 + col];
    float hp = hprev[i];
    float z = 1.f / (1.f + expf(-(xz + miz)));
    float hh = tanhf(xh + mh[i]);
    h[i] = z * hp + (1.f - z) * hh;
}

// ---------------- launch -----------------------------------------------------
extern "C" void kernel_launch(void* const* d_in, const int* in_sizes, int n_in,
                              void* d_out, int out_size, void* d_ws, size_t ws_size,
                              hipStream_t stream)
{
    (void)in_sizes; (void)n_in; (void)out_size; (void)ws_size;

    const float* inputs   = (const float*)d_in[0];   // 4096 x 4000
    const float* h_tm1    = (const float*)d_in[1];   // 4096 x 512
    const float* crohis   = (const float*)d_in[2];   // 4096 x 512
    const float* ew1      = (const float*)d_in[3];   // 2000 x 256
    const float* ew2      = (const float*)d_in[4];   // 2000 x 256
    const float* ca12w    = (const float*)d_in[5];
    const float* ca12u    = (const float*)d_in[6];
    const float* ca12v    = (const float*)d_in[7];
    const float* ca21w    = (const float*)d_in[8];
    const float* ca21u    = (const float*)d_in[9];
    const float* ca21v    = (const float*)d_in[10];
    const float* cw_w     = (const float*)d_in[11];  // 512 x 512 (crohis_weight_w)
    const float* cw_b     = (const float*)d_in[12];  // 512
    const float* cd_w     = (const float*)d_in[13];  // 512 x 512 (crohis_decomp_weight)
    const float* cd_b     = (const float*)d_in[14];  // 512
    const float* kern     = (const float*)d_in[15];  // 512 x 1536
    const float* rkern    = (const float*)d_in[16];  // 512 x 1536
    const float* bias     = (const float*)d_in[17];  // 1536

    float* ws = (float*)d_ws;
    const size_t MEG = 1048576;
    float* E     = ws + 0;            // 2M floats (4096x512)
    float* T     = ws + 2 * MEG;      // 4M floats (4096x1024)
    float* x     = ws + 6 * MEG;      // 2M
    float* cro   = ws + 8 * MEG;      // 2M
    float* hprev = ws + 10 * MEG;     // 2M
    float* mi2   = ws + 12 * MEG;     // 4M (4096x1024)
    float* rh    = ws + 16 * MEG;     // 2M   (also aliases Wcat: dead by then)
    float* mh    = ws + 18 * MEG;     // 2M
    float* Wcat  = ws + 16 * MEG;     // 0.5M (512x1024), dead after G3
    float* mx    = ws + 0;            // 6M, aliases E+T (dead after att_fuse)

    float* h_out   = (float*)d_out;            // 4096x512
    float* cro_out = (float*)d_out + 2 * MEG;  // 4096x512

    // pack combined attention weight
    pack_wcat<<<(512 * 1024 + 255) / 256, 256, 0, stream>>>(
        ca12w, ca12u, ca12v, ca21w, ca21u, ca21v, Wcat);

    // G1/G2: emb1, emb2 -> E   (K=2000)
    gemm64_pair<<<dim3(8, 64), 256, 0, stream>>>(
        inputs, inputs + 2000, 4000, ew1, ew2, 256, E, E + 256, 512, 2000, 4);

    // G3: T = E @ Wcat  (K=512)
    gemm64<0><<<dim3(16, 64), 256, 0, stream>>>(
        E, 512, Wcat, 1024, T, 1024, 512, nullptr, nullptr, 0);

    // attention + x + crohis_new
    att_fuse<<<4096, 256, 0, stream>>>(T, E, crohis, x, cro_out);

    // G4: cro = tanh(crohis @ cd_w + cd_b)
    gemm64<2><<<dim3(8, 64), 256, 0, stream>>>(
        crohis, 512, cd_w, 512, cro, 512, 512, cd_b, nullptr, 0);

    // G5: h_prev = h_tm1 + tanh(cro @ cw_w + cw_b)
    gemm64<3><<<dim3(8, 64), 256, 0, stream>>>(
        cro, 512, cw_w, 512, hprev, 512, 512, cw_b, h_tm1, 512);

    // G6: mx = x @ kernel + bias   (overwrites E/T region — both dead now)
    gemm64<1><<<dim3(24, 64), 256, 0, stream>>>(
        x, 512, kern, 1536, mx, 1536, 512, bias, nullptr, 0);

    // G7: mi2 = h_prev @ rkern[:, :1024]
    gemm64<0><<<dim3(16, 64), 256, 0, stream>>>(
        hprev, 512, rkern, 1536, mi2, 1024, 512, nullptr, nullptr, 0);

    // gates: rh = sigmoid(x_r + mi_r) * h_prev
    gru_gates<<<(4096 * 512) / 256, 256, 0, stream>>>(mx, mi2, hprev, rh);

    // G8: mh = (r*h_prev) @ rkern[:, 1024:]
    gemm64<0><<<dim3(8, 64), 256, 0, stream>>>(
        rh, 512, rkern + 1024, 1536, mh, 512, 512, nullptr, nullptr, 0);

    // GRU finalize -> h
    gru_final<<<(4096 * 512) / 256, 256, 0, stream>>>(mx, mi2, mh, hprev, h_out);
}

// Round 3
// 252.980 us; speedup vs baseline: 2.1815x; 2.1815x over previous
//
#include <hip/hip_runtime.h>
#include <hip/hip_bf16.h>
#include <math.h>

// DscaGRUCell rev 3 — all GEMMs in bf16 MFMA (16x16x32), m97-style structure:
// 128x128 tile, BK=32, 4 waves x (4x4) 16x16 frags, global_load_lds width-16,
// B pre-transposed (N x K) so A/B fragment reads are contiguous ds_read_b128.

#define TAU_F 0.5f

typedef __bf16 bf16x8 __attribute__((ext_vector_type(8)));
typedef float f32x4 __attribute__((ext_vector_type(4)));

__device__ __forceinline__ void gload16(const void* g, void* l) {
    __builtin_amdgcn_global_load_lds(
        (const __attribute__((address_space(1))) void*)g,
        (__attribute__((address_space(3))) void*)l, 16, 0, 0);
}

// FLAGS: 1=BIAS, 2=TANH, 4=BASE(add fp32 base), 8=store bf16, 16=store fp32
template <int FLAGS>
__global__ __launch_bounds__(256) void gemm_mfma(
    const __bf16* __restrict__ A, int lda,     // M x K row-major
    const __bf16* __restrict__ BT, int ldbt,   // N x K row-major (B^T)
    float* __restrict__ Cf, __bf16* __restrict__ Cb, int ldc,
    int K,
    const float* __restrict__ bias,
    const float* __restrict__ base, int ldbase,
    int pairSplitBx, int pairAOff)
{
    constexpr bool BIAS = (FLAGS & 1) != 0;
    constexpr bool TANH = (FLAGS & 2) != 0;
    constexpr bool BASE = (FLAGS & 4) != 0;
    constexpr bool SB   = (FLAGS & 8) != 0;
    constexpr bool SF   = (FLAGS & 16) != 0;

    __shared__ __bf16 As[128][32];
    __shared__ __bf16 Bs[128][32];

    const int tid = threadIdx.x;
    const int w = tid >> 6, l = tid & 63;
    if ((int)blockIdx.x >= pairSplitBx) A += pairAOff;
    const int brow = blockIdx.y * 128, bcol = blockIdx.x * 128;
    const int wr = (w >> 1) * 64, wc = (w & 1) * 64;

    // staging: wave w covers rows w*32 .. w*32+31 of each tile, 2 issues each
    const int sr = w * 32 + (l >> 2);
    const int seg = (l & 3) * 8;
    const __bf16* Ag0 = A + (size_t)(brow + sr) * lda + seg;
    const __bf16* Ag1 = Ag0 + (size_t)16 * lda;
    const __bf16* Bg0 = BT + (size_t)(bcol + sr) * ldbt + seg;
    const __bf16* Bg1 = Bg0 + (size_t)16 * ldbt;
    __bf16* Al0 = &As[w * 32][0];
    __bf16* Al1 = &As[w * 32 + 16][0];
    __bf16* Bl0 = &Bs[w * 32][0];
    __bf16* Bl1 = &Bs[w * 32 + 16][0];

    f32x4 acc[4][4] = {};
    const int fr = l & 15, fk = (l >> 4) * 8;

    for (int k0 = 0; k0 < K; k0 += 32) {
        __syncthreads();               // previous compute done before overwrite
        gload16(Ag0 + k0, Al0);
        gload16(Ag1 + k0, Al1);
        gload16(Bg0 + k0, Bl0);
        gload16(Bg1 + k0, Bl1);
        __syncthreads();               // drains vmcnt: tile visible
        bf16x8 a[4], b[4];
#pragma unroll
        for (int m = 0; m < 4; ++m) a[m] = *(const bf16x8*)&As[wr + m * 16 + fr][fk];
#pragma unroll
        for (int n = 0; n < 4; ++n) b[n] = *(const bf16x8*)&Bs[wc + n * 16 + fr][fk];
#pragma unroll
        for (int m = 0; m < 4; ++m)
#pragma unroll
            for (int n = 0; n < 4; ++n)
                acc[m][n] = __builtin_amdgcn_mfma_f32_16x16x32_bf16(a[m], b[n], acc[m][n], 0, 0, 0);
    }

    // epilogue: C/D layout col=lane&15, row=(lane>>4)*4+reg  [m89/m91]
    const int fq = (l >> 4) * 4;
#pragma unroll
    for (int m = 0; m < 4; ++m) {
#pragma unroll
        for (int n = 0; n < 4; ++n) {
#pragma unroll
            for (int r = 0; r < 4; ++r) {
                int row = brow + wr + m * 16 + fq + r;
                int col = bcol + wc + n * 16 + fr;
                float v = acc[m][n][r];
                if (BIAS) v += bias[col];
                if (TANH) v = tanhf(v);
                if (BASE) v += base[(size_t)row * ldbase + col];
                if (SF) Cf[(size_t)row * ldc + col] = v;
                if (SB) Cb[(size_t)row * ldc + col] = (__bf16)v;
            }
        }
    }
}

// ---------------- prep kernels ----------------------------------------------
// inputs (4096x4000 f32) -> Xb (4096x4096 bf16): cols 0..1999 = X1, 2048..4047 = X2, rest 0
__global__ __launch_bounds__(256) void cvt_inputs(
    const float* __restrict__ in, __bf16* __restrict__ out)
{
    int i = blockIdx.x * 256 + threadIdx.x;   // 0..16M
    int row = i >> 12, col = i & 4095;
    float v = 0.f;
    if (col < 2000) v = in[(size_t)row * 4000 + col];
    else if (col >= 2048 && col < 4048) v = in[(size_t)row * 4000 + (col - 48)];
    out[i] = (__bf16)v;
}

__global__ __launch_bounds__(256) void cvt_bf16(
    const float* __restrict__ in, __bf16* __restrict__ out, int n)
{
    int i = blockIdx.x * 256 + threadIdx.x;
    if (i < n) out[i] = (__bf16)in[i];
}

// in: K x N fp32 -> out: N x Kpad bf16 (transposed, zero-padded K)
__global__ __launch_bounds__(256) void transpose_pad(
    const float* __restrict__ in, __bf16* __restrict__ out,
    int K, int N, int Kpad, int total)
{
    int i = blockIdx.x * 256 + threadIdx.x;
    if (i >= total) return;
    int n = i / Kpad, k = i - n * Kpad;
    out[i] = (__bf16)((k < K) ? in[(size_t)k * N + n] : 0.f);
}

// WcatT (1024 x 512 bf16): WcatT[n][k] = Wcat[k][n], Wcat as in rev2 block layout
__global__ __launch_bounds__(256) void pack_wcatT(
    const float* __restrict__ w12, const float* __restrict__ u12,
    const float* __restrict__ v12, const float* __restrict__ w21,
    const float* __restrict__ u21, const float* __restrict__ v21,
    __bf16* __restrict__ out)
{
    int i = blockIdx.x * 256 + threadIdx.x;   // 1024*512
    if (i >= 1024 * 512) return;
    int n = i >> 9, k = i & 511;
    int jm = n & 255;
    bool khi = k >= 256;
    int kk = k & 255;
    float v;
    if (n < 256)      v = khi ? u12[kk * 256 + jm] : w12[kk * 256 + jm];
    else if (n < 512) v = khi ? w21[kk * 256 + jm] : u21[kk * 256 + jm];
    else if (n < 768) v = khi ? v12[kk * 256 + jm] : 0.f;
    else              v = khi ? 0.f : v21[kk * 256 + jm];
    out[i] = (__bf16)v;
}

// ---------------- attention softmax fuse ------------------------------------
__device__ inline float block_reduce_max(float v, volatile float* s4) {
#pragma unroll
    for (int o = 32; o >= 1; o >>= 1) v = fmaxf(v, __shfl_xor(v, o, 64));
    __syncthreads();
    if ((threadIdx.x & 63) == 0) s4[threadIdx.x >> 6] = v;
    __syncthreads();
    return fmaxf(fmaxf(s4[0], s4[1]), fmaxf(s4[2], s4[3]));
}
__device__ inline float block_reduce_sum(float v, volatile float* s4) {
#pragma unroll
    for (int o = 32; o >= 1; o >>= 1) v += __shfl_xor(v, o, 64);
    __syncthreads();
    if ((threadIdx.x & 63) == 0) s4[threadIdx.x >> 6] = v;
    __syncthreads();
    return s4[0] + s4[1] + s4[2] + s4[3];
}

__global__ __launch_bounds__(256) void att_fuse(
    const __bf16* __restrict__ T, const __bf16* __restrict__ E,
    const float* __restrict__ crohis, __bf16* __restrict__ x,
    float* __restrict__ cro_new)
{
    __shared__ float s4[4];
    const int row = blockIdx.x;
    const int j = threadIdx.x;
    const __bf16* t = T + (size_t)row * 1024;

    float s12 = tanhf((float)t[j])       * (float)t[512 + j];
    float s21 = tanhf((float)t[256 + j]) * (float)t[768 + j];

    float m12 = block_reduce_max(s12, s4);
    float e12 = expf(s12 - m12);
    float sum12 = block_reduce_sum(e12, s4);
    float m21 = block_reduce_max(s21, s4);
    float e21 = expf(s21 - m21);
    float sum21 = block_reduce_sum(e21, s4);

    float att12 = e12 / sum12;
    float att21 = e21 / sum21;

    size_t b0 = (size_t)row * 512 + j;
    size_t b1 = b0 + 256;
    float x1 = (float)E[b0] * att12;
    float x2 = (float)E[b1] * att21;
    x[b0] = (__bf16)x1;
    x[b1] = (__bf16)x2;
    cro_new[b0] = TAU_F * crohis[b0] + (1.f - TAU_F) * x1;
    cro_new[b1] = TAU_F * crohis[b1] + (1.f - TAU_F) * x2;
}

// ---------------- GRU gates: rh = sigmoid(x_r + mi_r) * h_prev --------------
__global__ __launch_bounds__(256) void gru_gates(
    const float* __restrict__ mx, const float* __restrict__ mi2,
    const float* __restrict__ hprev, __bf16* __restrict__ rh)
{
    int i = blockIdx.x * 256 + threadIdx.x;
    int row = i >> 9, col = i & 511;
    float xr  = mx[(size_t)row * 1536 + 512 + col];
    float mir = mi2[(size_t)row * 1024 + 512 + col];
    float r = 1.f / (1.f + expf(-(xr + mir)));
    rh[i] = (__bf16)(r * hprev[i]);
}

// ---------------- GRU finalize ----------------------------------------------
__global__ __launch_bounds__(256) void gru_final(
    const float* __restrict__ mx, const float* __restrict__ mi2,
    const float* __restrict__ mh, const float* __restrict__ hprev,
    float* __restrict__ h)
{
    int i = blockIdx.x * 256 + threadIdx.x;
    int row = i >> 9, col = i & 511;
    const float* mxr = mx + (size_t)row * 1536;
    float xz = mxr[col], xh = mxr[1024 + col];
    float miz = mi2[(size_t)row * 1024 + col];
    float hp = hprev[i];
    float z = 1.f / (1.f + expf(-(xz + miz)));
    float hh = tanhf(xh + mh[i]);
    h[i] = z * hp + (1.f - z) * hh;
}

// ---------------- launch -----------------------------------------------------
extern "C" void kernel_launch(void* const* d_in, const int* in_sizes, int n_in,
                              void* d_out, int out_size, void* d_ws, size_t ws_size,
                              hipStream_t stream)
{
    (void)in_sizes; (void)n_in; (void)out_size; (void)ws_size;

    const float* inputs = (const float*)d_in[0];
    const float* h_tm1  = (const float*)d_in[1];
    const float* crohis = (const float*)d_in[2];
    const float* ew1    = (const float*)d_in[3];
    const float* ew2    = (const float*)d_in[4];
    const float* ca12w  = (const float*)d_in[5];
    const float* ca12u  = (const float*)d_in[6];
    const float* ca12v  = (const float*)d_in[7];
    const float* ca21w  = (const float*)d_in[8];
    const float* ca21u  = (const float*)d_in[9];
    const float* ca21v  = (const float*)d_in[10];
    const float* cw_w   = (const float*)d_in[11];
    const float* cw_b   = (const float*)d_in[12];
    const float* cd_w   = (const float*)d_in[13];
    const float* cd_b   = (const float*)d_in[14];
    const float* kern   = (const float*)d_in[15];
    const float* rkern  = (const float*)d_in[16];
    const float* bias   = (const float*)d_in[17];

    char* ws = (char*)d_ws;
    const size_t MB = 1024 * 1024;
    __bf16* Xb        = (__bf16*)(ws + 0);        // 32MB, 4096x4096
    float*  mx        = (float*)(ws + 0);         // 24MB alias (after G12)
    __bf16* T         = (__bf16*)(ws + 32 * MB);  // 8MB, 4096x1024
    __bf16* E         = (__bf16*)(ws + 40 * MB);  // 4MB
    __bf16* x         = (__bf16*)(ws + 44 * MB);  // 4MB
    float*  mi2       = (float*)(ws + 32 * MB);   // 16MB alias over T/E/x (after G6)
    __bf16* crohis_bf = (__bf16*)(ws + 48 * MB);  // 4MB
    __bf16* cro_bf    = (__bf16*)(ws + 52 * MB);  // 4MB
    float*  mh        = (float*)(ws + 48 * MB);   // 8MB alias (after G5)
    float*  hprev     = (float*)(ws + 56 * MB);   // 8MB
    __bf16* hprev_bf  = (__bf16*)(ws + 64 * MB);  // 4MB
    __bf16* rh        = (__bf16*)(ws + 68 * MB);  // 4MB
    __bf16* WT        = (__bf16*)(ws + 72 * MB);  // 2MB, 512x2048
    __bf16* WcatT     = (__bf16*)(ws + 74 * MB);  // 1MB, 1024x512
    __bf16* cdT       = (__bf16*)(ws + 75 * MB);  // 0.5MB
    __bf16* cwT       = (__bf16*)(ws + 75 * MB + 512 * 1024);
    __bf16* kernT     = (__bf16*)(ws + 76 * MB);  // 1.5MB, 1536x512
    __bf16* rkernT    = (__bf16*)(ws + 77 * MB + 512 * 1024); // 1.5MB

    float* h_out   = (float*)d_out;
    float* cro_out = (float*)d_out + 2 * 1048576;

    const int NOSPLIT = 1 << 30;

    // ---- prep
    cvt_inputs<<<65536, 256, 0, stream>>>(inputs, Xb);
    cvt_bf16<<<8192, 256, 0, stream>>>(crohis, crohis_bf, 4096 * 512);
    transpose_pad<<<(256 * 2048 + 255) / 256, 256, 0, stream>>>(ew1, WT, 2000, 256, 2048, 256 * 2048);
    transpose_pad<<<(256 * 2048 + 255) / 256, 256, 0, stream>>>(ew2, WT + 256 * 2048, 2000, 256, 2048, 256 * 2048);
    pack_wcatT<<<(1024 * 512 + 255) / 256, 256, 0, stream>>>(ca12w, ca12u, ca12v, ca21w, ca21u, ca21v, WcatT);
    transpose_pad<<<(512 * 512 + 255) / 256, 256, 0, stream>>>(cd_w, cdT, 512, 512, 512, 512 * 512);
    transpose_pad<<<(512 * 512 + 255) / 256, 256, 0, stream>>>(cw_w, cwT, 512, 512, 512, 512 * 512);
    transpose_pad<<<(1536 * 512 + 255) / 256, 256, 0, stream>>>(kern, kernT, 512, 1536, 512, 1536 * 512);
    transpose_pad<<<(1536 * 512 + 255) / 256, 256, 0, stream>>>(rkern, rkernT, 512, 1536, 512, 1536 * 512);

    // ---- G12: E = [X1@W1 | X2@W2]   (K=2048 padded, paired A offset)
    gemm_mfma<8><<<dim3(4, 32), 256, 0, stream>>>(
        Xb, 4096, WT, 2048, nullptr, E, 512, 2048, nullptr, nullptr, 0, 2, 2048);

    // ---- G3: T = E @ Wcat
    gemm_mfma<8><<<dim3(8, 32), 256, 0, stream>>>(
        E, 512, WcatT, 512, nullptr, T, 1024, 512, nullptr, nullptr, 0, NOSPLIT, 0);

    // ---- attention + x + crohis_new
    att_fuse<<<4096, 256, 0, stream>>>(T, E, crohis, x, cro_out);

    // ---- G4: cro = tanh(crohis @ cd_w + cd_b)   (bf16 out)
    gemm_mfma<11><<<dim3(4, 32), 256, 0, stream>>>(
        crohis_bf, 512, cdT, 512, nullptr, cro_bf, 512, 512, cd_b, nullptr, 0, NOSPLIT, 0);

    // ---- G5: hprev = h_tm1 + tanh(cro @ cw_w + cw_b)   (fp32 + bf16 out)
    gemm_mfma<31><<<dim3(4, 32), 256, 0, stream>>>(
        cro_bf, 512, cwT, 512, hprev, hprev_bf, 512, 512, cw_b, h_tm1, 512, NOSPLIT, 0);

    // ---- G6: mx = x @ kernel + bias   (fp32, aliases Xb)
    gemm_mfma<17><<<dim3(12, 32), 256, 0, stream>>>(
        x, 512, kernT, 512, mx, nullptr, 1536, 512, bias, nullptr, 0, NOSPLIT, 0);

    // ---- G7: mi2 = hprev @ rkern[:, :1024]
    gemm_mfma<16><<<dim3(8, 32), 256, 0, stream>>>(
        hprev_bf, 512, rkernT, 512, mi2, nullptr, 1024, 512, nullptr, nullptr, 0, NOSPLIT, 0);

    // ---- gates: rh = sigmoid(x_r + mi_r) * h_prev
    gru_gates<<<(4096 * 512) / 256, 256, 0, stream>>>(mx, mi2, hprev, rh);

    // ---- G8: mh = rh @ rkern[:, 1024:]
    gemm_mfma<16><<<dim3(4, 32), 256, 0, stream>>>(
        rh, 512, rkernT + (size_t)1024 * 512, 512, mh, nullptr, 512, 512, nullptr, nullptr, 0, NOSPLIT, 0);

    // ---- finalize
    gru_final<<<(4096 * 512) / 256, 256, 0, stream>>>(mx, mi2, mh, hprev, h_out);
}

// Round 4
// 189.544 us; speedup vs baseline: 2.9117x; 1.3347x over previous
//
#include <hip/hip_runtime.h>
#include <hip/hip_bf16.h>
#include <math.h>

// DscaGRUCell rev 4 — occupancy-focused: dual-GEMM launches + split-K partials,
// fp32-A reg-staged conversion in the GEMM (no cvt_inputs pass), all epilogues
// fused into elementwise consumers.

#define TAU_F 0.5f

typedef __bf16 bf16x8 __attribute__((ext_vector_type(8)));
typedef __bf16 bf16x4 __attribute__((ext_vector_type(4)));
typedef float f32x4 __attribute__((ext_vector_type(4)));

__device__ __forceinline__ void gload16(const void* g, void* l) {
    __builtin_amdgcn_global_load_lds(
        (const __attribute__((address_space(1))) void*)g,
        (__attribute__((address_space(3))) void*)l, 16, 0, 0);
}

struct SubGemm {
    const void* A;   // M x lda, f32 (AFP32) or bf16
    int lda;         // elements
    int Kvalid;      // valid A cols (AFP32 path zero-fills beyond; mult of 16)
    const __bf16* BT;// N x Kpad row-major (pre-transposed, pre-padded bf16)
    int ldbt;
    float* C;        // fp32 partial out
    int ldc;
    long long strideC; // elements per split slice
    int Ksub;        // K per split slice (mult of 32); Kpad = S*Ksub
    int nbx;         // col tiles (N/128)
    int pairSplit;   // col tiles >= this use A + pairAOff
    int pairAOff;    // element offset
};

// 128x128 tile, BK=32, 4 waves x (4x4) 16x16x32 bf16 MFMA frags.
// Two sub-GEMMs per launch: blockIdx.x < blocks1 -> g1 else g2.
template <bool AFP32>
__global__ __launch_bounds__(256) void gemm_dual(SubGemm g1, SubGemm g2, int blocks1)
{
    __shared__ __bf16 As[128][32];
    __shared__ __bf16 Bs[128][32];

    const int tid = threadIdx.x;
    const int w = tid >> 6, l = tid & 63;

    const bool second = (int)blockIdx.x >= blocks1;
    const SubGemm& g = second ? g2 : g1;
    const int bxl = second ? (int)blockIdx.x - blocks1 : (int)blockIdx.x;
    const int ct  = bxl % g.nbx;
    const int spl = bxl / g.nbx;
    const int brow = blockIdx.y * 128;
    const int bcol = ct * 128;
    const int k_begin = spl * g.Ksub;
    const int k_end   = k_begin + g.Ksub;
    float* C = g.C + (size_t)spl * g.strideC;

    const int aoff = (ct >= g.pairSplit) ? g.pairAOff : 0;

    // B staging (bf16 gload_lds): wave w covers rows w*32..w*32+31, 2 issues
    const int sr = w * 32 + (l >> 2);
    const int seg = (l & 3) * 8;
    const __bf16* Bg0 = g.BT + (size_t)(bcol + sr) * g.ldbt + seg;
    const __bf16* Bg1 = Bg0 + (size_t)16 * g.ldbt;
    __bf16* Bl0 = &Bs[w * 32][0];
    __bf16* Bl1 = &Bs[w * 32 + 16][0];

    // A staging pointers
    const float*  Af = (const float*)g.A + aoff;
    const __bf16* Ab = (const __bf16*)g.A + aoff;
    const int arow = tid >> 1, acg = (tid & 1) * 16;        // AFP32 mapping
    const float* Afp = Af + (size_t)(brow + arow) * g.lda + acg;
    const __bf16* Ag0 = Ab + (size_t)(brow + sr) * g.lda + seg;
    const __bf16* Ag1 = Ag0 + (size_t)16 * g.lda;
    __bf16* Al0 = &As[w * 32][0];
    __bf16* Al1 = &As[w * 32 + 16][0];

    f32x4 acc[4][4] = {};
    const int fr = l & 15, fk = (l >> 4) * 8;

    for (int k0 = k_begin; k0 < k_end; k0 += 32) {
        __syncthreads();               // previous compute done before overwrite
        if (AFP32) {
            __bf16 bb[16];
#pragma unroll
            for (int q = 0; q < 4; ++q) {
                int kg = k0 + acg + q * 4;
                f32x4 v = {0.f, 0.f, 0.f, 0.f};
                if (kg < g.Kvalid) v = *(const f32x4*)(Afp + k0 + q * 4);
#pragma unroll
                for (int z = 0; z < 4; ++z) bb[q * 4 + z] = (__bf16)v[z];
            }
            *(bf16x8*)&As[arow][acg]     = *(bf16x8*)&bb[0];
            *(bf16x8*)&As[arow][acg + 8] = *(bf16x8*)&bb[8];
        } else {
            gload16(Ag0 + k0, Al0);
            gload16(Ag1 + k0, Al1);
        }
        gload16(Bg0 + k0, Bl0);
        gload16(Bg1 + k0, Bl1);
        __syncthreads();               // tile visible (vmcnt+lgkm drained)
        bf16x8 a[4], b[4];
        const int wr = (w >> 1) * 64, wc = (w & 1) * 64;
#pragma unroll
        for (int m = 0; m < 4; ++m) a[m] = *(const bf16x8*)&As[wr + m * 16 + fr][fk];
#pragma unroll
        for (int n = 0; n < 4; ++n) b[n] = *(const bf16x8*)&Bs[wc + n * 16 + fr][fk];
#pragma unroll
        for (int m = 0; m < 4; ++m)
#pragma unroll
            for (int n = 0; n < 4; ++n)
                acc[m][n] = __builtin_amdgcn_mfma_f32_16x16x32_bf16(a[m], b[n], acc[m][n], 0, 0, 0);
    }

    // epilogue: raw fp32 partial store. C/D layout: col=lane&15, row=(lane>>4)*4+reg
    const int wr = (w >> 1) * 64, wc = (w & 1) * 64;
    const int fq = (l >> 4) * 4;
#pragma unroll
    for (int m = 0; m < 4; ++m)
#pragma unroll
        for (int n = 0; n < 4; ++n)
#pragma unroll
            for (int r = 0; r < 4; ++r) {
                int row = brow + wr + m * 16 + fq + r;
                int col = bcol + wc + n * 16 + fr;
                C[(size_t)row * g.ldc + col] = acc[m][n][r];
            }
}

// ---------------- weight prep: all transposes/casts in one launch -----------
__global__ __launch_bounds__(256) void prep_w(
    const float* __restrict__ ew1, const float* __restrict__ ew2,
    const float* __restrict__ w12, const float* __restrict__ u12,
    const float* __restrict__ v12, const float* __restrict__ w21,
    const float* __restrict__ u21, const float* __restrict__ v21,
    const float* __restrict__ cd_w, const float* __restrict__ cw_w,
    const float* __restrict__ kern, const float* __restrict__ rkern,
    __bf16* __restrict__ WT, __bf16* __restrict__ WcatT,
    __bf16* __restrict__ cdT, __bf16* __restrict__ cwT,
    __bf16* __restrict__ kernT, __bf16* __restrict__ rkernT)
{
    int idx = blockIdx.x * 256 + threadIdx.x;
    if (idx < 1048576) {                       // WT: 512 x 2048 (rows 0..255 = W1^T)
        int n = idx >> 11, k = idx & 2047;
        float v = 0.f;
        if (k < 2000) v = (n < 256) ? ew1[(size_t)k * 256 + n]
                                    : ew2[(size_t)k * 256 + (n - 256)];
        WT[idx] = (__bf16)v;
        return;
    }
    idx -= 1048576;
    if (idx < 524288) {                        // WcatT: 1024 x 512
        int n = idx >> 9, k = idx & 511;
        int jm = n & 255; bool khi = k >= 256; int kk = k & 255;
        float v;
        if (n < 256)      v = khi ? u12[kk * 256 + jm] : w12[kk * 256 + jm];
        else if (n < 512) v = khi ? w21[kk * 256 + jm] : u21[kk * 256 + jm];
        else if (n < 768) v = khi ? v12[kk * 256 + jm] : 0.f;
        else              v = khi ? 0.f : v21[kk * 256 + jm];
        WcatT[idx] = (__bf16)v;
        return;
    }
    idx -= 524288;
    if (idx < 262144) {                        // cdT: 512 x 512
        int n = idx >> 9, k = idx & 511;
        cdT[idx] = (__bf16)cd_w[(size_t)k * 512 + n];
        return;
    }
    idx -= 262144;
    if (idx < 262144) {                        // cwT
        int n = idx >> 9, k = idx & 511;
        cwT[idx] = (__bf16)cw_w[(size_t)k * 512 + n];
        return;
    }
    idx -= 262144;
    if (idx < 786432) {                        // kernT: 1536 x 512
        int n = idx >> 9, k = idx & 511;
        kernT[idx] = (__bf16)kern[(size_t)k * 1536 + n];
        return;
    }
    idx -= 786432;
    if (idx < 786432) {                        // rkernT: 1536 x 512
        int n = idx >> 9, k = idx & 511;
        rkernT[idx] = (__bf16)rkern[(size_t)k * 1536 + n];
    }
}

// ---------------- R-A: E = bf16(sum P12), cro = bf16(tanh(sum P4 + cd_b)) ----
__global__ __launch_bounds__(256) void reduce_A(
    const float* __restrict__ P12, const float* __restrict__ P4,
    const float* __restrict__ cd_b,
    __bf16* __restrict__ E, __bf16* __restrict__ cro)
{
    int b = blockIdx.x;
    int i = (((b & 2047) * 256) + threadIdx.x) * 4;
    if (b < 2048) {
        f32x4 p0 = *(const f32x4*)(P12 + i);
        f32x4 p1 = *(const f32x4*)(P12 + (1 << 21) + i);
        __bf16 o[4];
#pragma unroll
        for (int j = 0; j < 4; ++j) o[j] = (__bf16)(p0[j] + p1[j]);
        *(bf16x4*)&E[i] = *(bf16x4*)o;
    } else {
        f32x4 p0 = *(const f32x4*)(P4 + i);
        f32x4 p1 = *(const f32x4*)(P4 + (1 << 21) + i);
        int c = i & 511;
        __bf16 o[4];
#pragma unroll
        for (int j = 0; j < 4; ++j) o[j] = (__bf16)tanhf(p0[j] + p1[j] + cd_b[c + j]);
        *(bf16x4*)&cro[i] = *(bf16x4*)o;
    }
}

// ---------------- fuse1: attention softmax + x + crohis_new, and hprev ------
__global__ __launch_bounds__(256) void fuse1(
    const float* __restrict__ T, const __bf16* __restrict__ E,
    const float* __restrict__ crohis,
    const float* __restrict__ P5_0,     // slice 0
    const float* __restrict__ h_tm1, const float* __restrict__ cw_b,
    __bf16* __restrict__ x, float* __restrict__ cro_out,
    float* hprev_io,                    // == P5 slice 1 (read sum-in, write hprev)
    __bf16* __restrict__ hprev_bf)
{
    __shared__ float s4[4];
    int b = blockIdx.x;
    int j = threadIdx.x;
    if (b < 4096) {
        const float* t = T + (size_t)b * 1024;
        float s12 = tanhf(t[j])       * t[512 + j];
        float s21 = tanhf(t[256 + j]) * t[768 + j];
        // max/sum reductions over 256 threads
        float v = s12;
#pragma unroll
        for (int o = 32; o >= 1; o >>= 1) v = fmaxf(v, __shfl_xor(v, o, 64));
        __syncthreads(); if ((j & 63) == 0) s4[j >> 6] = v; __syncthreads();
        float m12 = fmaxf(fmaxf(s4[0], s4[1]), fmaxf(s4[2], s4[3]));
        float e12 = expf(s12 - m12);
        v = e12;
#pragma unroll
        for (int o = 32; o >= 1; o >>= 1) v += __shfl_xor(v, o, 64);
        __syncthreads(); if ((j & 63) == 0) s4[j >> 6] = v; __syncthreads();
        float sum12 = s4[0] + s4[1] + s4[2] + s4[3];
        v = s21;
#pragma unroll
        for (int o = 32; o >= 1; o >>= 1) v = fmaxf(v, __shfl_xor(v, o, 64));
        __syncthreads(); if ((j & 63) == 0) s4[j >> 6] = v; __syncthreads();
        float m21 = fmaxf(fmaxf(s4[0], s4[1]), fmaxf(s4[2], s4[3]));
        float e21 = expf(s21 - m21);
        v = e21;
#pragma unroll
        for (int o = 32; o >= 1; o >>= 1) v += __shfl_xor(v, o, 64);
        __syncthreads(); if ((j & 63) == 0) s4[j >> 6] = v; __syncthreads();
        float sum21 = s4[0] + s4[1] + s4[2] + s4[3];

        size_t b0 = (size_t)b * 512 + j, b1 = b0 + 256;
        float x1 = (float)E[b0] * (e12 / sum12);
        float x2 = (float)E[b1] * (e21 / sum21);
        x[b0] = (__bf16)x1;
        x[b1] = (__bf16)x2;
        cro_out[b0] = TAU_F * crohis[b0] + (1.f - TAU_F) * x1;
        cro_out[b1] = TAU_F * crohis[b1] + (1.f - TAU_F) * x2;
    } else {
        int i = ((b - 4096) * 256 + j) * 4;
        f32x4 p0 = *(const f32x4*)(P5_0 + i);
        f32x4 p1 = *(const f32x4*)(hprev_io + i);   // P5 slice 1 (same slot)
        f32x4 ht = *(const f32x4*)(h_tm1 + i);
        int c = i & 511;
        f32x4 o; __bf16 ob[4];
#pragma unroll
        for (int q = 0; q < 4; ++q) {
            float hv = ht[q] + tanhf(p0[q] + p1[q] + cw_b[c + q]);
            o[q] = hv; ob[q] = (__bf16)hv;
        }
        *(f32x4*)(hprev_io + i) = o;
        *(bf16x4*)&hprev_bf[i] = *(bf16x4*)ob;
    }
}

// ---------------- gates: rh = sigmoid(mx_r + bias_r + mi_r) * hprev ----------
__global__ __launch_bounds__(256) void gates_k(
    const float* __restrict__ mx, const float* __restrict__ mi2,
    const float* __restrict__ hprev, const float* __restrict__ bias,
    __bf16* __restrict__ rh)
{
    int i = (blockIdx.x * 256 + threadIdx.x) * 4;
    int row = i >> 9, c = i & 511;
    f32x4 a  = *(const f32x4*)(mx + (size_t)row * 1536 + 512 + c);
    f32x4 m  = *(const f32x4*)(mi2 + (size_t)row * 1024 + 512 + c);
    f32x4 hp = *(const f32x4*)(hprev + i);
    f32x4 bb = *(const f32x4*)(bias + 512 + c);
    __bf16 o[4];
#pragma unroll
    for (int q = 0; q < 4; ++q) {
        float r = 1.f / (1.f + expf(-(a[q] + bb[q] + m[q])));
        o[q] = (__bf16)(r * hp[q]);
    }
    *(bf16x4*)&rh[i] = *(bf16x4*)o;
}

// ---------------- final: h -----------------------------------------------------
__global__ __launch_bounds__(256) void final_k(
    const float* __restrict__ mx, const float* __restrict__ mi2,
    const float* __restrict__ P8, const float* __restrict__ hprev,
    const float* __restrict__ bias, float* __restrict__ h)
{
    int i = (blockIdx.x * 256 + threadIdx.x) * 4;
    int row = i >> 9, c = i & 511;
    f32x4 xz = *(const f32x4*)(mx + (size_t)row * 1536 + c);
    f32x4 xh = *(const f32x4*)(mx + (size_t)row * 1536 + 1024 + c);
    f32x4 mz = *(const f32x4*)(mi2 + (size_t)row * 1024 + c);
    f32x4 p0 = *(const f32x4*)(P8 + i);
    f32x4 p1 = *(const f32x4*)(P8 + (1 << 21) + i);
    f32x4 hp = *(const f32x4*)(hprev + i);
    f32x4 bz = *(const f32x4*)(bias + c);
    f32x4 bh = *(const f32x4*)(bias + 1024 + c);
    f32x4 o;
#pragma unroll
    for (int q = 0; q < 4; ++q) {
        float z = 1.f / (1.f + expf(-(xz[q] + bz[q] + mz[q])));
        float hh = tanhf(xh[q] + bh[q] + p0[q] + p1[q]);
        o[q] = z * hp[q] + (1.f - z) * hh;
    }
    *(f32x4*)(h + i) = o;
}

// ---------------- launch -----------------------------------------------------
extern "C" void kernel_launch(void* const* d_in, const int* in_sizes, int n_in,
                              void* d_out, int out_size, void* d_ws, size_t ws_size,
                              hipStream_t stream)
{
    (void)in_sizes; (void)n_in; (void)out_size; (void)ws_size;

    const float* inputs = (const float*)d_in[0];
    const float* h_tm1  = (const float*)d_in[1];
    const float* crohis = (const float*)d_in[2];
    const float* ew1    = (const float*)d_in[3];
    const float* ew2    = (const float*)d_in[4];
    const float* ca12w  = (const float*)d_in[5];
    const float* ca12u  = (const float*)d_in[6];
    const float* ca12v  = (const float*)d_in[7];
    const float* ca21w  = (const float*)d_in[8];
    const float* ca21u  = (const float*)d_in[9];
    const float* ca21v  = (const float*)d_in[10];
    const float* cw_w   = (const float*)d_in[11];
    const float* cw_b   = (const float*)d_in[12];
    const float* cd_w   = (const float*)d_in[13];
    const float* cd_b   = (const float*)d_in[14];
    const float* kern   = (const float*)d_in[15];
    const float* rkern  = (const float*)d_in[16];
    const float* bias   = (const float*)d_in[17];

    char* ws = (char*)d_ws;
    const size_t MB = 1 << 20;
    float*  P12      = (float*)(ws + 0);         // 2 x 8MB (stride 2M elems)
    float*  P4       = (float*)(ws + 16 * MB);   // 2 x 8MB
    float*  T        = (float*)(ws + 0);         // 16MB (after R-A)
    float*  P5       = (float*)(ws + 16 * MB);   // slice0 @16MB, slice1 @24MB
    float*  hprev    = (float*)(ws + 24 * MB);   // 8MB (== P5 slice1 slot)
    float*  mx       = (float*)(ws + 0);         // 24MB (after fuse1)
    float*  mi2      = (float*)(ws + 32 * MB);   // 16MB
    __bf16* rh       = (__bf16*)(ws + 48 * MB);  // 4MB
    float*  P8       = (float*)(ws + 52 * MB);   // 2 x 8MB (after phase C)
    __bf16* E        = (__bf16*)(ws + 52 * MB);  // 4MB (dead before G8)
    __bf16* cro_bf   = (__bf16*)(ws + 56 * MB);  // 4MB
    __bf16* x        = (__bf16*)(ws + 60 * MB);  // 4MB
    __bf16* hprev_bf = (__bf16*)(ws + 64 * MB);  // 4MB
    __bf16* WT       = (__bf16*)(ws + 68 * MB);  // 2MB (512 x 2048)
    __bf16* WcatT    = (__bf16*)(ws + 70 * MB);  // 1MB (1024 x 512)
    __bf16* cdT      = (__bf16*)(ws + 71 * MB);  // 0.5MB
    __bf16* cwT      = (__bf16*)(ws + 71 * MB + 512 * 1024);
    __bf16* kernT    = (__bf16*)(ws + 72 * MB);  // 1.5MB (1536 x 512)
    __bf16* rkernT   = (__bf16*)(ws + 73 * MB + 512 * 1024); // 1.5MB -> ends 75MB

    float* h_out   = (float*)d_out;
    float* cro_out = (float*)d_out + 2 * 1048576;

    const int BIG = 1 << 30;
    const long long S2 = 1LL << 21;   // 2M-element split stride

    // ---- prep (weights only)
    prep_w<<<14336, 256, 0, stream>>>(ew1, ew2, ca12w, ca12u, ca12v, ca21w,
                                      ca21u, ca21v, cd_w, cw_w, kern, rkern,
                                      WT, WcatT, cdT, cwT, kernT, rkernT);

    // ---- Phase A: G12 (split-K=2) + G4 (split-K=2), fp32 A
    SubGemm gA1 = { inputs, 4000, 2000, WT, 2048, P12, 512, S2, 1024, 4, 2, 2000 };
    SubGemm gA2 = { crohis,  512,  512, cdT,  512, P4,  512, S2,  256, 4, BIG, 0 };
    gemm_dual<true><<<dim3(16, 32), 256, 0, stream>>>(gA1, gA2, 8);

    // ---- R-A
    reduce_A<<<4096, 256, 0, stream>>>(P12, P4, cd_b, E, cro_bf);

    // ---- Phase B: G3 (S=1) + G5 (split-K=2), bf16 A
    SubGemm gB1 = { E,      512, 512, WcatT, 512, T,  1024, 0,  512, 8, BIG, 0 };
    SubGemm gB2 = { cro_bf, 512, 512, cwT,   512, P5, 512,  S2, 256, 4, BIG, 0 };
    gemm_dual<false><<<dim3(16, 32), 256, 0, stream>>>(gB1, gB2, 8);

    // ---- fuse1: attention + x + crohis_new, and hprev
    fuse1<<<6144, 256, 0, stream>>>(T, E, crohis, P5, h_tm1, cw_b,
                                    x, cro_out, hprev, hprev_bf);

    // ---- Phase C: G6 (mx) + G7 (mi2)
    SubGemm gC1 = { x,        512, 512, kernT,  512, mx,  1536, 0, 512, 12, BIG, 0 };
    SubGemm gC2 = { hprev_bf, 512, 512, rkernT, 512, mi2, 1024, 0, 512, 8,  BIG, 0 };
    gemm_dual<false><<<dim3(20, 32), 256, 0, stream>>>(gC1, gC2, 12);

    // ---- gates
    gates_k<<<2048, 256, 0, stream>>>(mx, mi2, hprev, bias, rh);

    // ---- G8: mh partials (split-K=2)
    SubGemm gG = { rh, 512, 512, rkernT + (size_t)1024 * 512, 512, P8, 512, S2, 256, 4, BIG, 0 };
    gemm_dual<false><<<dim3(8, 32), 256, 0, stream>>>(gG, gG, 8);

    // ---- final
    final_k<<<2048, 256, 0, stream>>>(mx, mi2, P8, hprev, bias, h_out);
}

// Round 5
// 148.897 us; speedup vs baseline: 3.7065x; 1.2730x over previous
//
#include <hip/hip_runtime.h>
#include <hip/hip_bf16.h>
#include <math.h>

// DscaGRUCell rev 5 — latency-focused: 64x128 tiles (2x blocks), double-buffered
// 2-phase pipelined K-loop (T3 minimum), T14 reg-staged fp32->bf16 A path for
// phase A (no cvt pre-pass). Workspace repacked to 75 MB.

#define TAU_F 0.5f

typedef __bf16 bf16x8 __attribute__((ext_vector_type(8)));
typedef __bf16 bf16x4 __attribute__((ext_vector_type(4)));
typedef float f32x4 __attribute__((ext_vector_type(4)));

__device__ __forceinline__ void gload16(const void* g, void* l) {
    __builtin_amdgcn_global_load_lds(
        (const __attribute__((address_space(1))) void*)g,
        (__attribute__((address_space(3))) void*)l, 16, 0, 0);
}

struct SubGemm {
    const void* A;   // M x lda (f32 if AFP32 else bf16)
    int lda;         // elements
    int Kvalid;      // valid A cols (AFP32 path zero-fills beyond)
    const __bf16* BT;// N x Kpad row-major (pre-transposed, zero-padded bf16)
    int ldbt;
    float* C;        // fp32 partial out
    int ldc;
    long long strideC;
    int Ksub;        // K per split slice (mult of 32)
    int nbx;         // col tiles (N/128)
    int pairSplit;   // col tiles >= this use A + pairAOff
    int pairAOff;    // element offset
};

// 64x128 tile, BK=32, 4 waves as 2x2, each wave 2x4 frags of 16x16x32.
// Double-buffered LDS, one vmcnt(0)+barrier per K-step (tile t+1 in flight
// during tile t's MFMAs). AFP32: A reg-staged (load early, cvt+ds_write late).
template <bool AFP32>
__global__ __launch_bounds__(256) void gemm_dual(SubGemm g1, SubGemm g2, int blocks1)
{
    __shared__ __bf16 As[2][64][32];
    __shared__ __bf16 Bs[2][128][32];

    const int tid = threadIdx.x, w = tid >> 6, l = tid & 63;
    const bool second = (int)blockIdx.x >= blocks1;
    const SubGemm& g = second ? g2 : g1;
    const int bxl = second ? (int)blockIdx.x - blocks1 : (int)blockIdx.x;
    const int ct = bxl % g.nbx, spl = bxl / g.nbx;
    const int brow = (int)blockIdx.y * 64, bcol = ct * 128;
    const int k_begin = spl * g.Ksub;
    const int nt = g.Ksub >> 5;
    float* C = g.C + (size_t)spl * g.strideC;
    const int aoff = (ct >= g.pairSplit) ? g.pairAOff : 0;

    // staging geometry: lane covers (row, 8-col segment)
    const int sar = w * 16 + (l >> 2);        // A: wave w stages rows w*16..+15
    const int sbr = w * 32 + (l >> 2);        // B: rows w*32..+31 (2 issues)
    const int seg = (l & 3) * 8;

    const __bf16* Ab = (const __bf16*)g.A + aoff + (size_t)(brow + sar) * g.lda + seg + k_begin;
    const float*  Af = (const float*)g.A + aoff + (size_t)(brow + sar) * g.lda + seg + k_begin;
    const __bf16* Bg0 = g.BT + (size_t)(bcol + sbr) * g.ldbt + seg + k_begin;
    const __bf16* Bg1 = Bg0 + (size_t)16 * g.ldbt;

    f32x4 acc[2][4] = {};
    const int fr = l & 15, fk = (l >> 4) * 8;
    const int wr = (w >> 1) * 32, wc = (w & 1) * 64;

    // ---- prologue: stage tile 0 into buf 0
    if (AFP32) {
        int c0 = k_begin + seg;
        f32x4 v0 = {0,0,0,0}, v1 = {0,0,0,0};
        if (c0     < g.Kvalid) v0 = *(const f32x4*)(Af);
        if (c0 + 4 < g.Kvalid) v1 = *(const f32x4*)(Af + 4);
        gload16(Bg0, &Bs[0][w * 32][0]);
        gload16(Bg1, &Bs[0][w * 32 + 16][0]);
        asm volatile("s_waitcnt vmcnt(0)" ::: "memory");
        __bf16 o[8];
#pragma unroll
        for (int q = 0; q < 4; ++q) { o[q] = (__bf16)v0[q]; o[4 + q] = (__bf16)v1[q]; }
        *(bf16x8*)&As[0][sar][seg] = *(bf16x8*)o;
    } else {
        gload16(Ab, &As[0][w * 16][0]);
        gload16(Bg0, &Bs[0][w * 32][0]);
        gload16(Bg1, &Bs[0][w * 32 + 16][0]);
    }
    __syncthreads();

    int cur = 0;
    for (int t = 0; t < nt; ++t) {
        // ds_read current fragments FIRST (no vmem-LDS hazard in front of them)
        bf16x8 a[2], b[4];
#pragma unroll
        for (int m = 0; m < 2; ++m) a[m] = *(const bf16x8*)&As[cur][wr + m * 16 + fr][fk];
#pragma unroll
        for (int n = 0; n < 4; ++n) b[n] = *(const bf16x8*)&Bs[cur][wc + n * 16 + fr][fk];

        // issue next tile's loads (in flight across the MFMAs)
        f32x4 v0 = {0,0,0,0}, v1 = {0,0,0,0};
        const bool more = (t + 1 < nt);
        if (more) {
            const int k = (t + 1) * 32;
            if (AFP32) {
                int c0 = k_begin + seg + k;
                if (c0     < g.Kvalid) v0 = *(const f32x4*)(Af + k);
                if (c0 + 4 < g.Kvalid) v1 = *(const f32x4*)(Af + k + 4);
            } else {
                gload16(Ab + k, &As[cur ^ 1][w * 16][0]);
            }
            gload16(Bg0 + k, &Bs[cur ^ 1][w * 32][0]);
            gload16(Bg1 + k, &Bs[cur ^ 1][w * 32 + 16][0]);
        }

#pragma unroll
        for (int m = 0; m < 2; ++m)
#pragma unroll
            for (int n = 0; n < 4; ++n)
                acc[m][n] = __builtin_amdgcn_mfma_f32_16x16x32_bf16(a[m], b[n], acc[m][n], 0, 0, 0);

        if (AFP32 && more) {
            asm volatile("s_waitcnt vmcnt(0)" ::: "memory");   // reg loads done
            __bf16 o[8];
#pragma unroll
            for (int q = 0; q < 4; ++q) { o[q] = (__bf16)v0[q]; o[4 + q] = (__bf16)v1[q]; }
            *(bf16x8*)&As[cur ^ 1][sar][seg] = *(bf16x8*)o;
        }
        __syncthreads();   // drains vmcnt+lgkm: buf[cur^1] ready for next iter
        cur ^= 1;
    }

    // epilogue: raw fp32 partial store. C/D: col=lane&15, row=(lane>>4)*4+reg
    const int fq = (l >> 4) * 4;
#pragma unroll
    for (int m = 0; m < 2; ++m)
#pragma unroll
        for (int n = 0; n < 4; ++n)
#pragma unroll
            for (int r = 0; r < 4; ++r) {
                int row = brow + wr + m * 16 + fq + r;
                int col = bcol + wc + n * 16 + fr;
                C[(size_t)row * g.ldc + col] = acc[m][n][r];
            }
}

// ---------------- weight prep: all transposes/casts in one launch -----------
__global__ __launch_bounds__(256) void prep_w(
    const float* __restrict__ ew1, const float* __restrict__ ew2,
    const float* __restrict__ w12, const float* __restrict__ u12,
    const float* __restrict__ v12, const float* __restrict__ w21,
    const float* __restrict__ u21, const float* __restrict__ v21,
    const float* __restrict__ cd_w, const float* __restrict__ cw_w,
    const float* __restrict__ kern, const float* __restrict__ rkern,
    __bf16* __restrict__ WT, __bf16* __restrict__ WcatT,
    __bf16* __restrict__ cdT, __bf16* __restrict__ cwT,
    __bf16* __restrict__ kernT, __bf16* __restrict__ rkernT)
{
    int idx = blockIdx.x * 256 + threadIdx.x;
    if (idx < 1048576) {                       // WT: 512 x 2048
        int n = idx >> 11, k = idx & 2047;
        float v = 0.f;
        if (k < 2000) v = (n < 256) ? ew1[(size_t)k * 256 + n]
                                    : ew2[(size_t)k * 256 + (n - 256)];
        WT[idx] = (__bf16)v;
        return;
    }
    idx -= 1048576;
    if (idx < 524288) {                        // WcatT: 1024 x 512
        int n = idx >> 9, k = idx & 511;
        int jm = n & 255; bool khi = k >= 256; int kk = k & 255;
        float v;
        if (n < 256)      v = khi ? u12[kk * 256 + jm] : w12[kk * 256 + jm];
        else if (n < 512) v = khi ? w21[kk * 256 + jm] : u21[kk * 256 + jm];
        else if (n < 768) v = khi ? v12[kk * 256 + jm] : 0.f;
        else              v = khi ? 0.f : v21[kk * 256 + jm];
        WcatT[idx] = (__bf16)v;
        return;
    }
    idx -= 524288;
    if (idx < 262144) {                        // cdT: 512 x 512
        int n = idx >> 9, k = idx & 511;
        cdT[idx] = (__bf16)cd_w[(size_t)k * 512 + n];
        return;
    }
    idx -= 262144;
    if (idx < 262144) {                        // cwT
        int n = idx >> 9, k = idx & 511;
        cwT[idx] = (__bf16)cw_w[(size_t)k * 512 + n];
        return;
    }
    idx -= 262144;
    if (idx < 786432) {                        // kernT: 1536 x 512
        int n = idx >> 9, k = idx & 511;
        kernT[idx] = (__bf16)kern[(size_t)k * 1536 + n];
        return;
    }
    idx -= 786432;
    if (idx < 786432) {                        // rkernT: 1536 x 512
        int n = idx >> 9, k = idx & 511;
        rkernT[idx] = (__bf16)rkern[(size_t)k * 1536 + n];
    }
}

// ---------------- R-A: E = bf16(sum P12), cro = bf16(tanh(P4 + cd_b)) -------
__global__ __launch_bounds__(256) void reduce_A(
    const float* __restrict__ P12, const float* __restrict__ P4,
    const float* __restrict__ cd_b,
    __bf16* __restrict__ E, __bf16* __restrict__ cro)
{
    int b = blockIdx.x;
    int i = (((b & 2047) * 256) + threadIdx.x) * 4;
    if (b < 2048) {
        f32x4 p0 = *(const f32x4*)(P12 + i);
        f32x4 p1 = *(const f32x4*)(P12 + (1 << 21) + i);
        __bf16 o[4];
#pragma unroll
        for (int j = 0; j < 4; ++j) o[j] = (__bf16)(p0[j] + p1[j]);
        *(bf16x4*)&E[i] = *(bf16x4*)o;
    } else {
        f32x4 p0 = *(const f32x4*)(P4 + i);
        int c = i & 511;
        __bf16 o[4];
#pragma unroll
        for (int j = 0; j < 4; ++j) o[j] = (__bf16)tanhf(p0[j] + cd_b[c + j]);
        *(bf16x4*)&cro[i] = *(bf16x4*)o;
    }
}

// ---------------- fuse1: attention softmax + x + crohis_new, and hprev ------
__global__ __launch_bounds__(256) void fuse1(
    const float* __restrict__ T, const __bf16* __restrict__ E,
    const float* __restrict__ crohis,
    const float* __restrict__ P5,
    const float* __restrict__ h_tm1, const float* __restrict__ cw_b,
    __bf16* __restrict__ x, float* __restrict__ cro_out,
    float* __restrict__ hprev, __bf16* __restrict__ hprev_bf)
{
    __shared__ float s4[4];
    int b = blockIdx.x;
    int j = threadIdx.x;
    if (b < 4096) {
        const float* t = T + (size_t)b * 1024;
        float s12 = tanhf(t[j])       * t[512 + j];
        float s21 = tanhf(t[256 + j]) * t[768 + j];
        float v = s12;
#pragma unroll
        for (int o = 32; o >= 1; o >>= 1) v = fmaxf(v, __shfl_xor(v, o, 64));
        __syncthreads(); if ((j & 63) == 0) s4[j >> 6] = v; __syncthreads();
        float m12 = fmaxf(fmaxf(s4[0], s4[1]), fmaxf(s4[2], s4[3]));
        float e12 = expf(s12 - m12);
        v = e12;
#pragma unroll
        for (int o = 32; o >= 1; o >>= 1) v += __shfl_xor(v, o, 64);
        __syncthreads(); if ((j & 63) == 0) s4[j >> 6] = v; __syncthreads();
        float sum12 = s4[0] + s4[1] + s4[2] + s4[3];
        v = s21;
#pragma unroll
        for (int o = 32; o >= 1; o >>= 1) v = fmaxf(v, __shfl_xor(v, o, 64));
        __syncthreads(); if ((j & 63) == 0) s4[j >> 6] = v; __syncthreads();
        float m21 = fmaxf(fmaxf(s4[0], s4[1]), fmaxf(s4[2], s4[3]));
        float e21 = expf(s21 - m21);
        v = e21;
#pragma unroll
        for (int o = 32; o >= 1; o >>= 1) v += __shfl_xor(v, o, 64);
        __syncthreads(); if ((j & 63) == 0) s4[j >> 6] = v; __syncthreads();
        float sum21 = s4[0] + s4[1] + s4[2] + s4[3];

        size_t b0 = (size_t)b * 512 + j, b1 = b0 + 256;
        float x1 = (float)E[b0] * (e12 / sum12);
        float x2 = (float)E[b1] * (e21 / sum21);
        x[b0] = (__bf16)x1;
        x[b1] = (__bf16)x2;
        cro_out[b0] = TAU_F * crohis[b0] + (1.f - TAU_F) * x1;
        cro_out[b1] = TAU_F * crohis[b1] + (1.f - TAU_F) * x2;
    } else {
        int i = ((b - 4096) * 256 + j) * 4;
        f32x4 p = *(const f32x4*)(P5 + i);
        f32x4 ht = *(const f32x4*)(h_tm1 + i);
        int c = i & 511;
        f32x4 o; __bf16 ob[4];
#pragma unroll
        for (int q = 0; q < 4; ++q) {
            float hv = ht[q] + tanhf(p[q] + cw_b[c + q]);
            o[q] = hv; ob[q] = (__bf16)hv;
        }
        *(f32x4*)(hprev + i) = o;
        *(bf16x4*)&hprev_bf[i] = *(bf16x4*)ob;
    }
}

// ---------------- gates: rh = sigmoid(mx_r + bias_r + mi_r) * hprev ----------
__global__ __launch_bounds__(256) void gates_k(
    const float* __restrict__ mx, const float* __restrict__ mi2,
    const float* __restrict__ hprev, const float* __restrict__ bias,
    __bf16* __restrict__ rh)
{
    int i = (blockIdx.x * 256 + threadIdx.x) * 4;
    int row = i >> 9, c = i & 511;
    f32x4 a  = *(const f32x4*)(mx + (size_t)row * 1536 + 512 + c);
    f32x4 m  = *(const f32x4*)(mi2 + (size_t)row * 1024 + 512 + c);
    f32x4 hp = *(const f32x4*)(hprev + i);
    f32x4 bb = *(const f32x4*)(bias + 512 + c);
    __bf16 o[4];
#pragma unroll
    for (int q = 0; q < 4; ++q) {
        float r = 1.f / (1.f + expf(-(a[q] + bb[q] + m[q])));
        o[q] = (__bf16)(r * hp[q]);
    }
    *(bf16x4*)&rh[i] = *(bf16x4*)o;
}

// ---------------- final: h ---------------------------------------------------
__global__ __launch_bounds__(256) void final_k(
    const float* __restrict__ mx, const float* __restrict__ mi2,
    const float* __restrict__ P8a, const float* __restrict__ P8b,
    const float* __restrict__ hprev, const float* __restrict__ bias,
    float* __restrict__ h)
{
    int i = (blockIdx.x * 256 + threadIdx.x) * 4;
    int row = i >> 9, c = i & 511;
    f32x4 xz = *(const f32x4*)(mx + (size_t)row * 1536 + c);
    f32x4 xh = *(const f32x4*)(mx + (size_t)row * 1536 + 1024 + c);
    f32x4 mz = *(const f32x4*)(mi2 + (size_t)row * 1024 + c);
    f32x4 p0 = *(const f32x4*)(P8a + i);
    f32x4 p1 = *(const f32x4*)(P8b + i);
    f32x4 hp = *(const f32x4*)(hprev + i);
    f32x4 bz = *(const f32x4*)(bias + c);
    f32x4 bh = *(const f32x4*)(bias + 1024 + c);
    f32x4 o;
#pragma unroll
    for (int q = 0; q < 4; ++q) {
        float z = 1.f / (1.f + expf(-(xz[q] + bz[q] + mz[q])));
        float hh = tanhf(xh[q] + bh[q] + p0[q] + p1[q]);
        o[q] = z * hp[q] + (1.f - z) * hh;
    }
    *(f32x4*)(h + i) = o;
}

// ---------------- launch -----------------------------------------------------
extern "C" void kernel_launch(void* const* d_in, const int* in_sizes, int n_in,
                              void* d_out, int out_size, void* d_ws, size_t ws_size,
                              hipStream_t stream)
{
    (void)in_sizes; (void)n_in; (void)out_size; (void)ws_size;

    const float* inputs = (const float*)d_in[0];
    const float* h_tm1  = (const float*)d_in[1];
    const float* crohis = (const float*)d_in[2];
    const float* ew1    = (const float*)d_in[3];
    const float* ew2    = (const float*)d_in[4];
    const float* ca12w  = (const float*)d_in[5];
    const float* ca12u  = (const float*)d_in[6];
    const float* ca12v  = (const float*)d_in[7];
    const float* ca21w  = (const float*)d_in[8];
    const float* ca21u  = (const float*)d_in[9];
    const float* ca21v  = (const float*)d_in[10];
    const float* cw_w   = (const float*)d_in[11];
    const float* cw_b   = (const float*)d_in[12];
    const float* cd_w   = (const float*)d_in[13];
    const float* cd_b   = (const float*)d_in[14];
    const float* kern   = (const float*)d_in[15];
    const float* rkern  = (const float*)d_in[16];
    const float* bias   = (const float*)d_in[17];

    char* ws = (char*)d_ws;
    const size_t MB = 1 << 20;
    // lifetimes: A=[phase A], B=[phase B], C=[phase C]
    float*  P12      = (float*)(ws + 0);          // 2x8MB @0,8 (A) -> T (B) -> mx (C)
    float*  P4       = (float*)(ws + 16 * MB);    // 8MB (A) -> P5 (B) -> mx tail (C)
    float*  T        = (float*)(ws + 0);          // 16MB (B)
    float*  P5       = (float*)(ws + 16 * MB);    // 8MB (B)
    float*  mx       = (float*)(ws + 0);          // 24MB (C..final)
    float*  hprev    = (float*)(ws + 24 * MB);    // 8MB (fuse1..final)
    __bf16* E        = (__bf16*)(ws + 32 * MB);   // 4MB (reduce_A..fuse1)
    __bf16* rh       = (__bf16*)(ws + 32 * MB);   // 4MB (gates..G8, over dead E)
    __bf16* cro_bf   = (__bf16*)(ws + 36 * MB);   // 4MB (reduce_A..B)
    __bf16* x        = (__bf16*)(ws + 36 * MB);   // 4MB (fuse1..C, over dead cro_bf)
    __bf16* hprev_bf = (__bf16*)(ws + 40 * MB);   // 4MB (fuse1..C)
    float*  P8       = (float*)(ws + 36 * MB);    // s0 @36 (over dead x/hprev_bf), s1 @60
    float*  mi2      = (float*)(ws + 44 * MB);    // 16MB (C..final)
    __bf16* WT       = (__bf16*)(ws + 68 * MB);   // 2MB
    __bf16* WcatT    = (__bf16*)(ws + 70 * MB);   // 1MB
    __bf16* cdT      = (__bf16*)(ws + 71 * MB);   // 0.5MB
    __bf16* cwT      = (__bf16*)(ws + 71 * MB + 512 * 1024);
    __bf16* kernT    = (__bf16*)(ws + 72 * MB);   // 1.5MB
    __bf16* rkernT   = (__bf16*)(ws + 73 * MB + 512 * 1024);  // -> ends 75MB

    float* h_out   = (float*)d_out;
    float* cro_out = (float*)d_out + 2 * 1048576;

    const int BIG = 1 << 30;

    prep_w<<<14336, 256, 0, stream>>>(ew1, ew2, ca12w, ca12u, ca12v, ca21w,
                                      ca21u, ca21v, cd_w, cw_w, kern, rkern,
                                      WT, WcatT, cdT, cwT, kernT, rkernT);

    // Phase A: G12 (split-K=2, fp32 A) + G4 (fp32 A)
    SubGemm gA1 = { inputs, 4000, 2000, WT, 2048, P12, 512, 1ll << 21, 1024, 4, 2, 2000 };
    SubGemm gA2 = { crohis,  512,  512, cdT,  512, P4,  512, 0,         512, 4, BIG, 0 };
    gemm_dual<true><<<dim3(12, 64), 256, 0, stream>>>(gA1, gA2, 8);

    reduce_A<<<4096, 256, 0, stream>>>(P12, P4, cd_b, E, cro_bf);

    // Phase B: G3 + G5 (bf16 A)
    SubGemm gB1 = { E,      512, 512, WcatT, 512, T,  1024, 0, 512, 8, BIG, 0 };
    SubGemm gB2 = { cro_bf, 512, 512, cwT,   512, P5, 512,  0, 512, 4, BIG, 0 };
    gemm_dual<false><<<dim3(12, 64), 256, 0, stream>>>(gB1, gB2, 8);

    fuse1<<<6144, 256, 0, stream>>>(T, E, crohis, P5, h_tm1, cw_b,
                                    x, cro_out, hprev, hprev_bf);

    // Phase C: G6 (mx) + G7 (mi2)
    SubGemm gC1 = { x,        512, 512, kernT,  512, mx,  1536, 0, 512, 12, BIG, 0 };
    SubGemm gC2 = { hprev_bf, 512, 512, rkernT, 512, mi2, 1024, 0, 512, 8,  BIG, 0 };
    gemm_dual<false><<<dim3(20, 64), 256, 0, stream>>>(gC1, gC2, 12);

    gates_k<<<2048, 256, 0, stream>>>(mx, mi2, hprev, bias, rh);

    // G8: split-K=2, slices @36MB and @60MB (stride 6M elems)
    SubGemm gG = { rh, 512, 512, rkernT + (size_t)1024 * 512, 512, P8, 512, 6ll << 20, 256, 4, BIG, 0 };
    gemm_dual<false><<<dim3(8, 64), 256, 0, stream>>>(gG, gG, 8);

    final_k<<<2048, 256, 0, stream>>>(mx, mi2, P8, P8 + (6ll << 20), hprev, bias, h_out);
}

// Round 6
// 136.933 us; speedup vs baseline: 4.0303x; 1.0874x over previous
//
#include <hip/hip_runtime.h>
#include <hip/hip_bf16.h>
#include <math.h>

// DscaGRUCell rev 6 — counted-vmcnt 3-buffer pipeline (T3/T4) + XCD-chunked
// block swizzle (T1) in the GEMM. 64x128 tiles, BK=32, 4 waves (2x4 frags).
// fp32-A path keeps T14 reg-staging with address-clamped (branchless) loads so
// per-wave vmem op counts are exec-independent (vmcnt immediates stay valid).

#define TAU_F 0.5f

typedef __bf16 bf16x8 __attribute__((ext_vector_type(8)));
typedef __bf16 bf16x4 __attribute__((ext_vector_type(4)));
typedef float f32x4 __attribute__((ext_vector_type(4)));

__device__ __forceinline__ void gload16(const void* g, void* l) {
    __builtin_amdgcn_global_load_lds(
        (const __attribute__((address_space(1))) void*)g,
        (__attribute__((address_space(3))) void*)l, 16, 0, 0);
}

struct SubGemm {
    const void* A;   // M x lda (f32 if AFP32 else bf16)
    int lda;         // elements
    int Kvalid;      // valid A cols; BT zero-padded beyond, so A reads clamp
    const __bf16* BT;// N x Kpad row-major (pre-transposed, zero-padded bf16)
    int ldbt;
    float* C;        // fp32 partial out
    int ldc;
    long long strideC;
    int Ksub;        // K per split slice (mult of 32, >= 256)
    int nbx;         // col tiles (N/128)
    int pairSplit;   // col tiles >= this use A + pairAOff
    int pairAOff;    // element offset
};

// Pipeline schedule (3 LDS bufs, depth 2):
//  prologue: issue tiles 0,1
//  step t:   wait vmcnt(K) [K=3 bf16 / 2 fp32A: tile t's loads done, newer stay
//            in flight]; lgkmcnt(0); s_barrier; ds_read frags(buf t);
//            [fp32A: ds_write A_{t+1}]; issue tile t+2 loads; MFMA.
// vmcnt counts verified per boundary; guards are wave-uniform so per-wave
// outstanding-op counts match the immediates.
template <bool AFP32>
__global__ __launch_bounds__(256) void gemm_dual(SubGemm g1, SubGemm g2, int blocks1)
{
    __shared__ __bf16 As[3][64][32];
    __shared__ __bf16 Bs[3][128][32];

    const int tid = threadIdx.x, w = tid >> 6, l = tid & 63;

    // T1: XCD-chunked swizzle. hw-consecutive blocks round-robin XCDs; remap so
    // each XCD gets a contiguous logical range (same-by blocks co-resident).
    const int gx = gridDim.x;
    const int nwg = gx * (int)gridDim.y;          // always % 8 == 0 here
    const int hw = (int)blockIdx.y * gx + (int)blockIdx.x;
    const int lg = (hw & 7) * (nwg >> 3) + (hw >> 3);
    const int bxl_lin = lg % gx;
    const int by = lg / gx;

    const bool second = bxl_lin >= blocks1;
    const SubGemm& g = second ? g2 : g1;
    const int bxl = second ? bxl_lin - blocks1 : bxl_lin;
    const int ct = bxl % g.nbx, spl = bxl / g.nbx;
    const int brow = by * 64, bcol = ct * 128;
    const int k_begin = spl * g.Ksub;
    const int nt = g.Ksub >> 5;
    float* C = g.C + (size_t)spl * g.strideC;
    const int aoff = (ct >= g.pairSplit) ? g.pairAOff : 0;

    // staging geometry
    const int sar = w * 16 + (l >> 2);        // A: wave w stages rows w*16..+15
    const int sbr = w * 32 + (l >> 2);        // B: rows w*32..+31 (2 issues)
    const int seg = (l & 3) * 8;

    const float*  AfRow = (const float*)g.A + aoff + (size_t)(brow + sar) * g.lda;
    const __bf16* AbRow = (const __bf16*)g.A + aoff + (size_t)(brow + sar) * g.lda + seg + k_begin;
    const __bf16* Bg0 = g.BT + (size_t)(bcol + sbr) * g.ldbt + seg + k_begin;
    const __bf16* Bg1 = Bg0 + (size_t)16 * g.ldbt;
    const int kcl = g.Kvalid - 8;             // address clamp (B^T zero-padded)

    f32x4 acc[2][4] = {};
    const int fr = l & 15, fk = (l >> 4) * 8;
    const int wr = (w >> 1) * 32, wc = (w & 1) * 64;

    f32x4 v0, v1;
    // ---- prologue: tiles 0 and 1
    if constexpr (AFP32) {
        { int col = k_begin + seg; col = col < kcl ? col : kcl;
          v0 = *(const f32x4*)(AfRow + col); v1 = *(const f32x4*)(AfRow + col + 4); }
        gload16(Bg0, &Bs[0][w * 32][0]);
        gload16(Bg1, &Bs[0][w * 32 + 16][0]);
        asm volatile("s_waitcnt vmcnt(2)" ::: "memory");     // regA0 done
        { __bf16 o[8];
#pragma unroll
          for (int z = 0; z < 4; ++z) { o[z] = (__bf16)v0[z]; o[4 + z] = (__bf16)v1[z]; }
          *(bf16x8*)&As[0][sar][seg] = *(bf16x8*)o; }
        { int col = k_begin + 32 + seg; col = col < kcl ? col : kcl;
          v0 = *(const f32x4*)(AfRow + col); v1 = *(const f32x4*)(AfRow + col + 4); }
        gload16(Bg0 + 32, &Bs[1][w * 32][0]);
        gload16(Bg1 + 32, &Bs[1][w * 32 + 16][0]);
    } else {
        gload16(AbRow,      &As[0][w * 16][0]);
        gload16(Bg0,        &Bs[0][w * 32][0]);
        gload16(Bg1,        &Bs[0][w * 32 + 16][0]);
        gload16(AbRow + 32, &As[1][w * 16][0]);
        gload16(Bg0 + 32,   &Bs[1][w * 32][0]);
        gload16(Bg1 + 32,   &Bs[1][w * 32 + 16][0]);
    }

    int b0 = 0, b1 = 1, b2 = 2;
    for (int t = 0; t < nt; ++t) {
        if (t < nt - 1) {
            if constexpr (AFP32) asm volatile("s_waitcnt vmcnt(2)" ::: "memory");
            else                 asm volatile("s_waitcnt vmcnt(3)" ::: "memory");
        } else {
            asm volatile("s_waitcnt vmcnt(0)" ::: "memory");
        }
        asm volatile("s_waitcnt lgkmcnt(0)" ::: "memory");
        __builtin_amdgcn_s_barrier();          // raw: does NOT drain vmcnt

        bf16x8 a[2], b[4];
#pragma unroll
        for (int m = 0; m < 2; ++m) a[m] = *(const bf16x8*)&As[b0][wr + m * 16 + fr][fk];
#pragma unroll
        for (int n = 0; n < 4; ++n) b[n] = *(const bf16x8*)&Bs[b0][wc + n * 16 + fr][fk];

        if constexpr (AFP32) {
            if (t + 1 < nt) {                  // ds_write A_{t+1} (regs from t-1)
                __bf16 o[8];
#pragma unroll
                for (int z = 0; z < 4; ++z) { o[z] = (__bf16)v0[z]; o[4 + z] = (__bf16)v1[z]; }
                *(bf16x8*)&As[b1][sar][seg] = *(bf16x8*)o;
            }
            if (t + 2 < nt) {                  // issue tile t+2
                const int k = (t + 2) * 32;
                int col = k_begin + k + seg; col = col < kcl ? col : kcl;
                v0 = *(const f32x4*)(AfRow + col);
                v1 = *(const f32x4*)(AfRow + col + 4);
                gload16(Bg0 + k, &Bs[b2][w * 32][0]);
                gload16(Bg1 + k, &Bs[b2][w * 32 + 16][0]);
            }
        } else {
            if (t + 2 < nt) {
                const int k = (t + 2) * 32;
                gload16(AbRow + k, &As[b2][w * 16][0]);
                gload16(Bg0 + k,   &Bs[b2][w * 32][0]);
                gload16(Bg1 + k,   &Bs[b2][w * 32 + 16][0]);
            }
        }

#pragma unroll
        for (int m = 0; m < 2; ++m)
#pragma unroll
            for (int n = 0; n < 4; ++n)
                acc[m][n] = __builtin_amdgcn_mfma_f32_16x16x32_bf16(a[m], b[n], acc[m][n], 0, 0, 0);

        const int tmp = b0; b0 = b1; b1 = b2; b2 = tmp;
    }

    // epilogue: raw fp32 partial store. C/D: col=lane&15, row=(lane>>4)*4+reg
    const int fq = (l >> 4) * 4;
#pragma unroll
    for (int m = 0; m < 2; ++m)
#pragma unroll
        for (int n = 0; n < 4; ++n)
#pragma unroll
            for (int r = 0; r < 4; ++r) {
                int row = brow + wr + m * 16 + fq + r;
                int col = bcol + wc + n * 16 + fr;
                C[(size_t)row * g.ldc + col] = acc[m][n][r];
            }
}

// ---------------- weight prep: all transposes/casts in one launch -----------
__global__ __launch_bounds__(256) void prep_w(
    const float* __restrict__ ew1, const float* __restrict__ ew2,
    const float* __restrict__ w12, const float* __restrict__ u12,
    const float* __restrict__ v12, const float* __restrict__ w21,
    const float* __restrict__ u21, const float* __restrict__ v21,
    const float* __restrict__ cd_w, const float* __restrict__ cw_w,
    const float* __restrict__ kern, const float* __restrict__ rkern,
    __bf16* __restrict__ WT, __bf16* __restrict__ WcatT,
    __bf16* __restrict__ cdT, __bf16* __restrict__ cwT,
    __bf16* __restrict__ kernT, __bf16* __restrict__ rkernT)
{
    int idx = blockIdx.x * 256 + threadIdx.x;
    if (idx < 1048576) {                       // WT: 512 x 2048
        int n = idx >> 11, k = idx & 2047;
        float v = 0.f;
        if (k < 2000) v = (n < 256) ? ew1[(size_t)k * 256 + n]
                                    : ew2[(size_t)k * 256 + (n - 256)];
        WT[idx] = (__bf16)v;
        return;
    }
    idx -= 1048576;
    if (idx < 524288) {                        // WcatT: 1024 x 512
        int n = idx >> 9, k = idx & 511;
        int jm = n & 255; bool khi = k >= 256; int kk = k & 255;
        float v;
        if (n < 256)      v = khi ? u12[kk * 256 + jm] : w12[kk * 256 + jm];
        else if (n < 512) v = khi ? w21[kk * 256 + jm] : u21[kk * 256 + jm];
        else if (n < 768) v = khi ? v12[kk * 256 + jm] : 0.f;
        else              v = khi ? 0.f : v21[kk * 256 + jm];
        WcatT[idx] = (__bf16)v;
        return;
    }
    idx -= 524288;
    if (idx < 262144) {                        // cdT: 512 x 512
        int n = idx >> 9, k = idx & 511;
        cdT[idx] = (__bf16)cd_w[(size_t)k * 512 + n];
        return;
    }
    idx -= 262144;
    if (idx < 262144) {                        // cwT
        int n = idx >> 9, k = idx & 511;
        cwT[idx] = (__bf16)cw_w[(size_t)k * 512 + n];
        return;
    }
    idx -= 262144;
    if (idx < 786432) {                        // kernT: 1536 x 512
        int n = idx >> 9, k = idx & 511;
        kernT[idx] = (__bf16)kern[(size_t)k * 1536 + n];
        return;
    }
    idx -= 786432;
    if (idx < 786432) {                        // rkernT: 1536 x 512
        int n = idx >> 9, k = idx & 511;
        rkernT[idx] = (__bf16)rkern[(size_t)k * 1536 + n];
    }
}

// ---------------- R-A: E = bf16(sum P12), cro = bf16(tanh(P4 + cd_b)) -------
__global__ __launch_bounds__(256) void reduce_A(
    const float* __restrict__ P12, const float* __restrict__ P4,
    const float* __restrict__ cd_b,
    __bf16* __restrict__ E, __bf16* __restrict__ cro)
{
    int b = blockIdx.x;
    int i = (((b & 2047) * 256) + threadIdx.x) * 4;
    if (b < 2048) {
        f32x4 p0 = *(const f32x4*)(P12 + i);
        f32x4 p1 = *(const f32x4*)(P12 + (1 << 21) + i);
        __bf16 o[4];
#pragma unroll
        for (int j = 0; j < 4; ++j) o[j] = (__bf16)(p0[j] + p1[j]);
        *(bf16x4*)&E[i] = *(bf16x4*)o;
    } else {
        f32x4 p0 = *(const f32x4*)(P4 + i);
        int c = i & 511;
        __bf16 o[4];
#pragma unroll
        for (int j = 0; j < 4; ++j) o[j] = (__bf16)tanhf(p0[j] + cd_b[c + j]);
        *(bf16x4*)&cro[i] = *(bf16x4*)o;
    }
}

// ---------------- fuse1: attention softmax + x + crohis_new, and hprev ------
__global__ __launch_bounds__(256) void fuse1(
    const float* __restrict__ T, const __bf16* __restrict__ E,
    const float* __restrict__ crohis,
    const float* __restrict__ P5,
    const float* __restrict__ h_tm1, const float* __restrict__ cw_b,
    __bf16* __restrict__ x, float* __restrict__ cro_out,
    float* __restrict__ hprev, __bf16* __restrict__ hprev_bf)
{
    __shared__ float s4[4];
    int b = blockIdx.x;
    int j = threadIdx.x;
    if (b < 4096) {
        const float* t = T + (size_t)b * 1024;
        float s12 = tanhf(t[j])       * t[512 + j];
        float s21 = tanhf(t[256 + j]) * t[768 + j];
        float v = s12;
#pragma unroll
        for (int o = 32; o >= 1; o >>= 1) v = fmaxf(v, __shfl_xor(v, o, 64));
        __syncthreads(); if ((j & 63) == 0) s4[j >> 6] = v; __syncthreads();
        float m12 = fmaxf(fmaxf(s4[0], s4[1]), fmaxf(s4[2], s4[3]));
        float e12 = expf(s12 - m12);
        v = e12;
#pragma unroll
        for (int o = 32; o >= 1; o >>= 1) v += __shfl_xor(v, o, 64);
        __syncthreads(); if ((j & 63) == 0) s4[j >> 6] = v; __syncthreads();
        float sum12 = s4[0] + s4[1] + s4[2] + s4[3];
        v = s21;
#pragma unroll
        for (int o = 32; o >= 1; o >>= 1) v = fmaxf(v, __shfl_xor(v, o, 64));
        __syncthreads(); if ((j & 63) == 0) s4[j >> 6] = v; __syncthreads();
        float m21 = fmaxf(fmaxf(s4[0], s4[1]), fmaxf(s4[2], s4[3]));
        float e21 = expf(s21 - m21);
        v = e21;
#pragma unroll
        for (int o = 32; o >= 1; o >>= 1) v += __shfl_xor(v, o, 64);
        __syncthreads(); if ((j & 63) == 0) s4[j >> 6] = v; __syncthreads();
        float sum21 = s4[0] + s4[1] + s4[2] + s4[3];

        size_t b0 = (size_t)b * 512 + j, b1 = b0 + 256;
        float x1 = (float)E[b0] * (e12 / sum12);
        float x2 = (float)E[b1] * (e21 / sum21);
        x[b0] = (__bf16)x1;
        x[b1] = (__bf16)x2;
        cro_out[b0] = TAU_F * crohis[b0] + (1.f - TAU_F) * x1;
        cro_out[b1] = TAU_F * crohis[b1] + (1.f - TAU_F) * x2;
    } else {
        int i = ((b - 4096) * 256 + j) * 4;
        f32x4 p = *(const f32x4*)(P5 + i);
        f32x4 ht = *(const f32x4*)(h_tm1 + i);
        int c = i & 511;
        f32x4 o; __bf16 ob[4];
#pragma unroll
        for (int q = 0; q < 4; ++q) {
            float hv = ht[q] + tanhf(p[q] + cw_b[c + q]);
            o[q] = hv; ob[q] = (__bf16)hv;
        }
        *(f32x4*)(hprev + i) = o;
        *(bf16x4*)&hprev_bf[i] = *(bf16x4*)ob;
    }
}

// ---------------- gates: rh = sigmoid(mx_r + bias_r + mi_r) * hprev ----------
__global__ __launch_bounds__(256) void gates_k(
    const float* __restrict__ mx, const float* __restrict__ mi2,
    const float* __restrict__ hprev, const float* __restrict__ bias,
    __bf16* __restrict__ rh)
{
    int i = (blockIdx.x * 256 + threadIdx.x) * 4;
    int row = i >> 9, c = i & 511;
    f32x4 a  = *(const f32x4*)(mx + (size_t)row * 1536 + 512 + c);
    f32x4 m  = *(const f32x4*)(mi2 + (size_t)row * 1024 + 512 + c);
    f32x4 hp = *(const f32x4*)(hprev + i);
    f32x4 bb = *(const f32x4*)(bias + 512 + c);
    __bf16 o[4];
#pragma unroll
    for (int q = 0; q < 4; ++q) {
        float r = 1.f / (1.f + expf(-(a[q] + bb[q] + m[q])));
        o[q] = (__bf16)(r * hp[q]);
    }
    *(bf16x4*)&rh[i] = *(bf16x4*)o;
}

// ---------------- final: h ---------------------------------------------------
__global__ __launch_bounds__(256) void final_k(
    const float* __restrict__ mx, const float* __restrict__ mi2,
    const float* __restrict__ P8a, const float* __restrict__ P8b,
    const float* __restrict__ hprev, const float* __restrict__ bias,
    float* __restrict__ h)
{
    int i = (blockIdx.x * 256 + threadIdx.x) * 4;
    int row = i >> 9, c = i & 511;
    f32x4 xz = *(const f32x4*)(mx + (size_t)row * 1536 + c);
    f32x4 xh = *(const f32x4*)(mx + (size_t)row * 1536 + 1024 + c);
    f32x4 mz = *(const f32x4*)(mi2 + (size_t)row * 1024 + c);
    f32x4 p0 = *(const f32x4*)(P8a + i);
    f32x4 p1 = *(const f32x4*)(P8b + i);
    f32x4 hp = *(const f32x4*)(hprev + i);
    f32x4 bz = *(const f32x4*)(bias + c);
    f32x4 bh = *(const f32x4*)(bias + 1024 + c);
    f32x4 o;
#pragma unroll
    for (int q = 0; q < 4; ++q) {
        float z = 1.f / (1.f + expf(-(xz[q] + bz[q] + mz[q])));
        float hh = tanhf(xh[q] + bh[q] + p0[q] + p1[q]);
        o[q] = z * hp[q] + (1.f - z) * hh;
    }
    *(f32x4*)(h + i) = o;
}

// ---------------- launch -----------------------------------------------------
extern "C" void kernel_launch(void* const* d_in, const int* in_sizes, int n_in,
                              void* d_out, int out_size, void* d_ws, size_t ws_size,
                              hipStream_t stream)
{
    (void)in_sizes; (void)n_in; (void)out_size; (void)ws_size;

    const float* inputs = (const float*)d_in[0];
    const float* h_tm1  = (const float*)d_in[1];
    const float* crohis = (const float*)d_in[2];
    const float* ew1    = (const float*)d_in[3];
    const float* ew2    = (const float*)d_in[4];
    const float* ca12w  = (const float*)d_in[5];
    const float* ca12u  = (const float*)d_in[6];
    const float* ca12v  = (const float*)d_in[7];
    const float* ca21w  = (const float*)d_in[8];
    const float* ca21u  = (const float*)d_in[9];
    const float* ca21v  = (const float*)d_in[10];
    const float* cw_w   = (const float*)d_in[11];
    const float* cw_b   = (const float*)d_in[12];
    const float* cd_w   = (const float*)d_in[13];
    const float* cd_b   = (const float*)d_in[14];
    const float* kern   = (const float*)d_in[15];
    const float* rkern  = (const float*)d_in[16];
    const float* bias   = (const float*)d_in[17];

    char* ws = (char*)d_ws;
    const size_t MB = 1 << 20;
    float*  P12      = (float*)(ws + 0);          // 2x8MB (A) -> T (B) -> mx (C)
    float*  P4       = (float*)(ws + 16 * MB);    // 8MB (A) -> P5 (B) -> mx tail (C)
    float*  T        = (float*)(ws + 0);          // 16MB (B)
    float*  P5       = (float*)(ws + 16 * MB);    // 8MB (B)
    float*  mx       = (float*)(ws + 0);          // 24MB (C..final)
    float*  hprev    = (float*)(ws + 24 * MB);    // 8MB (fuse1..final)
    __bf16* E        = (__bf16*)(ws + 32 * MB);   // 4MB (reduce_A..fuse1)
    __bf16* rh       = (__bf16*)(ws + 32 * MB);   // 4MB (gates..G8, over dead E)
    __bf16* cro_bf   = (__bf16*)(ws + 36 * MB);   // 4MB (reduce_A..B)
    __bf16* x        = (__bf16*)(ws + 36 * MB);   // 4MB (fuse1..C)
    __bf16* hprev_bf = (__bf16*)(ws + 40 * MB);   // 4MB (fuse1..C)
    float*  P8       = (float*)(ws + 36 * MB);    // s0 @36, s1 @60
    float*  mi2      = (float*)(ws + 44 * MB);    // 16MB (C..final)
    __bf16* WT       = (__bf16*)(ws + 68 * MB);   // 2MB
    __bf16* WcatT    = (__bf16*)(ws + 70 * MB);   // 1MB
    __bf16* cdT      = (__bf16*)(ws + 71 * MB);   // 0.5MB
    __bf16* cwT      = (__bf16*)(ws + 71 * MB + 512 * 1024);
    __bf16* kernT    = (__bf16*)(ws + 72 * MB);   // 1.5MB
    __bf16* rkernT   = (__bf16*)(ws + 73 * MB + 512 * 1024);  // -> ends 75MB

    float* h_out   = (float*)d_out;
    float* cro_out = (float*)d_out + 2 * 1048576;

    const int BIG = 1 << 30;

    prep_w<<<14336, 256, 0, stream>>>(ew1, ew2, ca12w, ca12u, ca12v, ca21w,
                                      ca21u, ca21v, cd_w, cw_w, kern, rkern,
                                      WT, WcatT, cdT, cwT, kernT, rkernT);

    // Phase A: G12 (split-K=2, fp32 A) + G4 (fp32 A)    [nwg=768, %8==0]
    SubGemm gA1 = { inputs, 4000, 2000, WT, 2048, P12, 512, 1ll << 21, 1024, 4, 2, 2000 };
    SubGemm gA2 = { crohis,  512,  512, cdT,  512, P4,  512, 0,         512, 4, BIG, 0 };
    gemm_dual<true><<<dim3(12, 64), 256, 0, stream>>>(gA1, gA2, 8);

    reduce_A<<<4096, 256, 0, stream>>>(P12, P4, cd_b, E, cro_bf);

    // Phase B: G3 + G5 (bf16 A)                          [nwg=768]
    SubGemm gB1 = { E,      512, 512, WcatT, 512, T,  1024, 0, 512, 8, BIG, 0 };
    SubGemm gB2 = { cro_bf, 512, 512, cwT,   512, P5, 512,  0, 512, 4, BIG, 0 };
    gemm_dual<false><<<dim3(12, 64), 256, 0, stream>>>(gB1, gB2, 8);

    fuse1<<<6144, 256, 0, stream>>>(T, E, crohis, P5, h_tm1, cw_b,
                                    x, cro_out, hprev, hprev_bf);

    // Phase C: G6 (mx) + G7 (mi2)                        [nwg=1280]
    SubGemm gC1 = { x,        512, 512, kernT,  512, mx,  1536, 0, 512, 12, BIG, 0 };
    SubGemm gC2 = { hprev_bf, 512, 512, rkernT, 512, mi2, 1024, 0, 512, 8,  BIG, 0 };
    gemm_dual<false><<<dim3(20, 64), 256, 0, stream>>>(gC1, gC2, 12);

    gates_k<<<2048, 256, 0, stream>>>(mx, mi2, hprev, bias, rh);

    // G8: split-K=2, slices @36MB and @60MB              [nwg=512]
    SubGemm gG = { rh, 512, 512, rkernT + (size_t)1024 * 512, 512, P8, 512, 6ll << 20, 256, 4, BIG, 0 };
    gemm_dual<false><<<dim3(8, 64), 256, 0, stream>>>(gG, gG, 8);

    final_k<<<2048, 256, 0, stream>>>(mx, mi2, P8, P8 + (6ll << 20), hprev, bias, h_out);
}